// Round 6
// baseline (2433.776 us; speedup 1.0000x reference)
//
#include <hip/hip_runtime.h>
#include <hip/hip_bf16.h>

// ============================================================================
// Net_72662256713812 — round 9: dispatch diet (78 -> 40 launches/forward).
//  - r8 lesson: attn won 62us but 13 added cvtw launches ate it. Launch
//    overhead ~4-6us x ~78 dispatches is a top-level cost.
//  - all f32->bf16 weight converts now in-kernel (drop 27 cvtw); expert A
//    gather in-kernel via sorted[] with clamp (drop 8 gathera; fixes latent
//    OOB read); attn reads mk/mv directly (drop fillmem x2; kbuf/vbuf plain
//    [B*T][D]); PE fused into fsmn (drop addpe). Bit-identical rounding.
// ============================================================================

typedef __bf16 bf16x8 __attribute__((ext_vector_type(8)));
typedef float f32x4 __attribute__((ext_vector_type(4)));

#define B_ 4
#define T_ 512
#define IN_ 80
#define OUT_ 4096
#define D_ 512
#define HID_ 1024
#define E_ 4
#define H_ 8
#define DH_ 64
#define M_ 64
#define BT_ (B_ * T_)        // 2048
#define TKV_ (T_ + M_)       // 576
#define RBLK_ (BT_ / 4)      // 512 router blocks

__device__ __forceinline__ unsigned pk2(float a, float b) {
    unsigned short ua = __builtin_bit_cast(unsigned short, (__bf16)a);
    unsigned short ub = __builtin_bit_cast(unsigned short, (__bf16)b);
    return (unsigned)ua | ((unsigned)ub << 16);
}

// ---------------------------------------------------------------- embed w1 (f32, K=80)
__global__ __launch_bounds__(256) void gemm80_k(
    const float* __restrict__ A,    // [BT_][80]
    const float* __restrict__ Bw,   // [80][1024]
    const float* __restrict__ bias, // [1024]
    float* __restrict__ C)          // [BT_][1024]
{
    __shared__ float As[80][68];   // [k][m]
    __shared__ float Bs[80][68];   // [k][n]
    int m0 = blockIdx.y * 64, n0 = blockIdx.x * 64;
    int tid = threadIdx.x;
#pragma unroll
    for (int i = 0; i < 5; i++) {
        int idx = tid + 256 * i;          // 0..1279
        int m = idx / 20, c = idx % 20;
        float4 f = *(const float4*)&A[(size_t)(m0 + m) * 80 + c * 4];
        As[c * 4 + 0][m] = f.x; As[c * 4 + 1][m] = f.y;
        As[c * 4 + 2][m] = f.z; As[c * 4 + 3][m] = f.w;
    }
#pragma unroll
    for (int i = 0; i < 5; i++) {
        int idx = tid + 256 * i;
        int k = idx / 16, c = idx % 16;
        float4 f = *(const float4*)&Bw[(size_t)k * 1024 + n0 + c * 4];
        *(float4*)&Bs[k][c * 4] = f;
    }
    __syncthreads();
    int tx = tid & 15, ty = tid >> 4;
    float acc[4][4];
#pragma unroll
    for (int j = 0; j < 4; j++)
#pragma unroll
        for (int i = 0; i < 4; i++) acc[j][i] = 0.f;
#pragma unroll 8
    for (int k = 0; k < 80; k++) {
        float4 a = *(const float4*)&As[k][ty * 4];
        float4 b = *(const float4*)&Bs[k][tx * 4];
        float av[4] = {a.x, a.y, a.z, a.w};
        float bv[4] = {b.x, b.y, b.z, b.w};
#pragma unroll
        for (int j = 0; j < 4; j++)
#pragma unroll
            for (int i = 0; i < 4; i++) acc[j][i] += av[j] * bv[i];
    }
#pragma unroll
    for (int j = 0; j < 4; j++) {
        size_t row = (size_t)(m0 + ty * 4 + j);
        float4 o;
        o.x = fmaxf(acc[j][0] + bias[n0 + tx * 4 + 0], 0.f);
        o.y = fmaxf(acc[j][1] + bias[n0 + tx * 4 + 1], 0.f);
        o.z = fmaxf(acc[j][2] + bias[n0 + tx * 4 + 2], 0.f);
        o.w = fmaxf(acc[j][3] + bias[n0 + tx * 4 + 3], 0.f);
        *(float4*)&C[row * 1024 + n0 + tx * 4] = o;
    }
}

// ---------------------------------------------------------------- R2 = emb_w2 @ router_l (f64 accum)
__global__ void wr2_k(const float* __restrict__ w2,   // [1024][512]
                      const float* __restrict__ r0,   // [512][4]
                      const float* __restrict__ rl,   // [7][512][4]
                      float* __restrict__ R2)         // [8][1024][4]
{
    int wv = threadIdx.x >> 6, lane = threadIdx.x & 63;
    int h = blockIdx.x * 4 + wv;
    const float* wrow = w2 + (size_t)h * 512;
    float w[8];
#pragma unroll
    for (int i = 0; i < 8; i++) w[i] = wrow[lane + 64 * i];
    for (int l = 0; l < 8; l++) {
        const float* rp = (l == 0) ? r0 : rl + (size_t)(l - 1) * 2048;
        double a0 = 0, a1 = 0, a2 = 0, a3 = 0;
#pragma unroll
        for (int i = 0; i < 8; i++) {
            int d = lane + 64 * i;
            float4 r = *(const float4*)&rp[d * 4];
            a0 += (double)w[i] * (double)r.x;
            a1 += (double)w[i] * (double)r.y;
            a2 += (double)w[i] * (double)r.z;
            a3 += (double)w[i] * (double)r.w;
        }
        for (int off = 32; off; off >>= 1) {
            a0 += __shfl_xor(a0, off); a1 += __shfl_xor(a1, off);
            a2 += __shfl_xor(a2, off); a3 += __shfl_xor(a3, off);
        }
        if (lane == 0) {
            float4 o = make_float4((float)a0, (float)a1, (float)a2, (float)a3);
            *(float4*)&R2[((size_t)l * 1024 + h) * 4] = o;
        }
    }
}

// ---------------------------------------------------------------- all-layers routing from h
__global__ __launch_bounds__(256) void routerall_k(
    const float* __restrict__ h,    // [BT_][1024]
    const float* __restrict__ R2,   // [8][1024][4]
    const int* __restrict__ seq_len,
    int* __restrict__ eid,          // [8][BT_]
    float* __restrict__ gatev,      // [8][BT_]
    float* __restrict__ impPart)    // [RBLK_][32]
{
    __shared__ float impLoc[4][32];
    int wv = threadIdx.x >> 6, lane = threadIdx.x & 63;
    int tok = blockIdx.x * 4 + wv;
    const float* hr = h + (size_t)tok * 1024;
    float acc[8][4];
#pragma unroll
    for (int l = 0; l < 8; l++)
#pragma unroll
        for (int e = 0; e < 4; e++) acc[l][e] = 0.f;
    for (int i = 0; i < 16; i++) {
        int d = lane + 64 * i;
        float hv = hr[d];
#pragma unroll
        for (int l = 0; l < 8; l++) {
            float4 r = *(const float4*)&R2[((size_t)l * 1024 + d) * 4];
            acc[l][0] += hv * r.x; acc[l][1] += hv * r.y;
            acc[l][2] += hv * r.z; acc[l][3] += hv * r.w;
        }
    }
    for (int off = 32; off; off >>= 1) {
#pragma unroll
        for (int l = 0; l < 8; l++)
#pragma unroll
            for (int e = 0; e < 4; e++) acc[l][e] += __shfl_xor(acc[l][e], off);
    }
    if (lane == 0) {
        int b = tok >> 9, t = tok & 511;
        bool valid = t < seq_len[b];
        for (int l = 0; l < 8; l++) {
            float lg[4] = {acc[l][0], acc[l][1], acc[l][2], acc[l][3]};
            float mx = fmaxf(fmaxf(lg[0], lg[1]), fmaxf(lg[2], lg[3]));
            float g[4], s = 0.f;
            for (int e = 0; e < 4; e++) { g[e] = expf(lg[e] - mx); s += g[e]; }
            float inv = 1.f / s;
            int am = 0; float bv = g[0];
            for (int e = 1; e < 4; e++) if (g[e] > bv) { bv = g[e]; am = e; }
            eid[l * BT_ + tok] = am;
            gatev[l * BT_ + tok] = bv * inv;
            for (int e = 0; e < 4; e++)
                impLoc[wv][l * 4 + e] = valid ? g[e] * inv : 0.f;
        }
    }
    __syncthreads();
    int tid = threadIdx.x;
    if (tid < 32) {
        float s = impLoc[0][tid] + impLoc[1][tid] + impLoc[2][tid] + impLoc[3][tid];
        impPart[(size_t)blockIdx.x * 32 + tid] = s;
    }
}

// ---------------------------------------------------------------- pipelined expert GEMM
// In-kernel f32->bf16 convert + A gather (W1OUT) — no prep kernels.
// W1OUT: A = Af f32, gathered via sorted[]; C = Cb bf16 relu(acc+bias), sorted order.
// else : A = Ah bf16 dense sorted; C = Cf f32 scatter, *scale.
template<bool W1OUT>
__global__ __launch_bounds__(256) void egemm_k(
    const float* __restrict__ Af, int lda, int Ks,
    const __bf16* __restrict__ Ah,
    const float* __restrict__ Bw,        // f32 [E][Ks][N]
    const float* __restrict__ bias,      // [E][N]
    __bf16* __restrict__ Cb, float* __restrict__ Cf,
    int N, int Kpad,
    const int* __restrict__ seg, const int* __restrict__ sorted,
    const float* __restrict__ scale)
{
    __shared__ __align__(16) __bf16 As[2][128 * 64];
    __shared__ __align__(16) __bf16 Bs[2][64 * 64];

    int e = blockIdx.z;
    int row0 = seg[e], cnt = seg[e + 1] - row0;
    int m0 = blockIdx.y * 128;
    if (m0 >= cnt) return;
    int n0 = blockIdx.x * 64;
    const float* Bp = Bw + (size_t)e * Ks * N;

    int tid = threadIdx.x;
    int arow = tid >> 1, ahalf = tid & 1;
    int mclamp = min(m0 + arow, cnt - 1);           // clamp (r7/r8 latent OOB fixed)
    const float*  afp = nullptr;
    const __bf16* ahp = nullptr;
    if (W1OUT) afp = Af + (size_t)sorted[row0 + mclamp] * lda + ahalf * 32;
    else       ahp = Ah + (size_t)(row0 + mclamp) * Kpad + ahalf * 32;
    int asb = arow * 64, ac0 = ahalf * 4, arx = arow & 7;
    int bn = tid & 63, bkc = tid >> 6;
    const float* bptr = Bp + n0 + bn;
    int bsb = bn * 64, brx = bn & 7;

    int lane = tid & 63, wid = tid >> 6;
    int wm = wid & 1, wn = wid >> 1;
    int l15 = lane & 15, quad = lane >> 4;

    int aoff[4][2], boff[2][2];
#pragma unroll
    for (int mt = 0; mt < 4; mt++) {
        int m = wm * 64 + mt * 16 + l15;
#pragma unroll
        for (int s = 0; s < 2; s++)
            aoff[mt][s] = m * 64 + (((s * 4 + quad) ^ (m & 7)) * 8);
    }
#pragma unroll
    for (int nt = 0; nt < 2; nt++) {
        int n = wn * 32 + nt * 16 + l15;
#pragma unroll
        for (int s = 0; s < 2; s++)
            boff[nt][s] = n * 64 + (((s * 4 + quad) ^ (n & 7)) * 8);
    }

    f32x4 acc[4][2];
#pragma unroll
    for (int mt = 0; mt < 4; mt++)
#pragma unroll
        for (int nt = 0; nt < 2; nt++)
#pragma unroll
            for (int r = 0; r < 4; r++) acc[mt][nt][r] = 0.f;

    uint4 rA[4]; unsigned rB[8];
    auto stage = [&](int k0) {
        if (W1OUT) {
#pragma unroll
            for (int j = 0; j < 4; j++) {
                int kg = ahalf * 32 + k0 + j * 8;
                if (kg < Ks) {
                    float4 f0 = *(const float4*)(afp + k0 + j * 8);
                    float4 f1 = *(const float4*)(afp + k0 + j * 8 + 4);
                    rA[j] = make_uint4(pk2(f0.x, f0.y), pk2(f0.z, f0.w),
                                       pk2(f1.x, f1.y), pk2(f1.z, f1.w));
                } else rA[j] = make_uint4(0, 0, 0, 0);
            }
        } else {
#pragma unroll
            for (int j = 0; j < 4; j++) rA[j] = *(const uint4*)(ahp + k0 + j * 8);
        }
#pragma unroll
        for (int c = 0; c < 2; c++) {
            int kk = k0 + (bkc * 2 + c) * 8;
#pragma unroll
            for (int i = 0; i < 4; i++) {
                int ka = kk + 2 * i, kb = ka + 1;
                float fa = (ka < Ks) ? bptr[(size_t)ka * N] : 0.f;
                float fb = (kb < Ks) ? bptr[(size_t)kb * N] : 0.f;
                rB[c * 4 + i] = pk2(fa, fb);
            }
        }
    };
    auto commit = [&](int buf) {
#pragma unroll
        for (int j = 0; j < 4; j++)
            *(uint4*)&As[buf][asb + (((ac0 + j) ^ arx) * 8)] = rA[j];
#pragma unroll
        for (int c = 0; c < 2; c++)
            *(uint4*)&Bs[buf][bsb + (((bkc * 2 + c) ^ brx) * 8)] =
                make_uint4(rB[c * 4 + 0], rB[c * 4 + 1], rB[c * 4 + 2], rB[c * 4 + 3]);
    };

    stage(0); commit(0); __syncthreads();
    int nt_ = Kpad >> 6;
    for (int t = 0; t < nt_; t++) {
        int buf = t & 1;
        if (t + 1 < nt_) stage((t + 1) << 6);
        bf16x8 af[4][2], bfr[2][2];
#pragma unroll
        for (int mt = 0; mt < 4; mt++)
#pragma unroll
            for (int s = 0; s < 2; s++)
                af[mt][s] = *(const bf16x8*)&As[buf][aoff[mt][s]];
#pragma unroll
        for (int ntx = 0; ntx < 2; ntx++)
#pragma unroll
            for (int s = 0; s < 2; s++)
                bfr[ntx][s] = *(const bf16x8*)&Bs[buf][boff[ntx][s]];
#pragma unroll
        for (int mt = 0; mt < 4; mt++)
#pragma unroll
            for (int ntx = 0; ntx < 2; ntx++)
#pragma unroll
                for (int s = 0; s < 2; s++)
                    acc[mt][ntx] = __builtin_amdgcn_mfma_f32_16x16x32_bf16(
                        af[mt][s], bfr[ntx][s], acc[mt][ntx], 0, 0, 0);
        if (t + 1 < nt_) commit(buf ^ 1);
        __syncthreads();
    }

#pragma unroll
    for (int mt = 0; mt < 4; mt++) {
#pragma unroll
        for (int r = 0; r < 4; r++) {
            int m = m0 + wm * 64 + mt * 16 + quad * 4 + r;
            if (m >= cnt) continue;
            if (W1OUT) {
                size_t ci = (size_t)(row0 + m);
#pragma unroll
                for (int ntx = 0; ntx < 2; ntx++) {
                    int col = n0 + wn * 32 + ntx * 16 + l15;
                    float v = acc[mt][ntx][r] + bias[e * N + col];
                    Cb[ci * N + col] = (__bf16)fmaxf(v, 0.f);
                }
            } else {
                int tok = sorted[row0 + m];
                float sc = scale[tok];
#pragma unroll
                for (int ntx = 0; ntx < 2; ntx++) {
                    int col = n0 + wn * 32 + ntx * 16 + l15;
                    Cf[(size_t)tok * N + col] = acc[mt][ntx][r] * sc;
                }
            }
        }
    }
}

// ---------------------------------------------------------------- pipelined dense GEMM (A f32, B f32, in-kernel cvt)
template<bool BIAS>
__global__ __launch_bounds__(256) void dgemm_k(
    const float* __restrict__ A,          // [2048][K] f32
    const float* __restrict__ Bw,         // [K][N] f32
    const float* __restrict__ bias,
    float* __restrict__ C,                // [2048][N]
    int N, int K)
{
    __shared__ __align__(16) __bf16 As[2][128 * 64];
    __shared__ __align__(16) __bf16 Bs[2][64 * 64];

    int m0 = blockIdx.y * 128, n0 = blockIdx.x * 64;
    int tid = threadIdx.x;
    int arow = tid >> 1, ahalf = tid & 1;
    const float* aptr = A + (size_t)(m0 + arow) * K + ahalf * 32;
    int asb = arow * 64, ac0 = ahalf * 4, arx = arow & 7;
    int bn = tid & 63, bkc = tid >> 6;
    const float* bptr = Bw + n0 + bn;
    int bsb = bn * 64, brx = bn & 7;

    int lane = tid & 63, wid = tid >> 6;
    int wm = wid & 1, wn = wid >> 1;
    int l15 = lane & 15, quad = lane >> 4;

    int aoff[4][2], boff[2][2];
#pragma unroll
    for (int mt = 0; mt < 4; mt++) {
        int m = wm * 64 + mt * 16 + l15;
#pragma unroll
        for (int s = 0; s < 2; s++)
            aoff[mt][s] = m * 64 + (((s * 4 + quad) ^ (m & 7)) * 8);
    }
#pragma unroll
    for (int nt = 0; nt < 2; nt++) {
        int n = wn * 32 + nt * 16 + l15;
#pragma unroll
        for (int s = 0; s < 2; s++)
            boff[nt][s] = n * 64 + (((s * 4 + quad) ^ (n & 7)) * 8);
    }

    f32x4 acc[4][2];
#pragma unroll
    for (int mt = 0; mt < 4; mt++)
#pragma unroll
        for (int nt = 0; nt < 2; nt++)
#pragma unroll
            for (int r = 0; r < 4; r++) acc[mt][nt][r] = 0.f;

    uint4 rA[4]; unsigned rB[8];
    auto stage = [&](int k0) {
#pragma unroll
        for (int j = 0; j < 4; j++) {
            float4 f0 = *(const float4*)(aptr + k0 + j * 8);
            float4 f1 = *(const float4*)(aptr + k0 + j * 8 + 4);
            rA[j] = make_uint4(pk2(f0.x, f0.y), pk2(f0.z, f0.w),
                               pk2(f1.x, f1.y), pk2(f1.z, f1.w));
        }
#pragma unroll
        for (int c = 0; c < 2; c++) {
            int kk = k0 + (bkc * 2 + c) * 8;
#pragma unroll
            for (int i = 0; i < 4; i++)
                rB[c * 4 + i] = pk2(bptr[(size_t)(kk + 2 * i) * N],
                                    bptr[(size_t)(kk + 2 * i + 1) * N]);
        }
    };
    auto commit = [&](int buf) {
#pragma unroll
        for (int j = 0; j < 4; j++)
            *(uint4*)&As[buf][asb + (((ac0 + j) ^ arx) * 8)] = rA[j];
#pragma unroll
        for (int c = 0; c < 2; c++)
            *(uint4*)&Bs[buf][bsb + (((bkc * 2 + c) ^ brx) * 8)] =
                make_uint4(rB[c * 4 + 0], rB[c * 4 + 1], rB[c * 4 + 2], rB[c * 4 + 3]);
    };

    stage(0); commit(0); __syncthreads();
    int nt_ = K >> 6;
    for (int t = 0; t < nt_; t++) {
        int buf = t & 1;
        if (t + 1 < nt_) stage((t + 1) << 6);
        bf16x8 af[4][2], bfr[2][2];
#pragma unroll
        for (int mt = 0; mt < 4; mt++)
#pragma unroll
            for (int s = 0; s < 2; s++)
                af[mt][s] = *(const bf16x8*)&As[buf][aoff[mt][s]];
#pragma unroll
        for (int ntx = 0; ntx < 2; ntx++)
#pragma unroll
            for (int s = 0; s < 2; s++)
                bfr[ntx][s] = *(const bf16x8*)&Bs[buf][boff[ntx][s]];
#pragma unroll
        for (int mt = 0; mt < 4; mt++)
#pragma unroll
            for (int ntx = 0; ntx < 2; ntx++)
#pragma unroll
                for (int s = 0; s < 2; s++)
                    acc[mt][ntx] = __builtin_amdgcn_mfma_f32_16x16x32_bf16(
                        af[mt][s], bfr[ntx][s], acc[mt][ntx], 0, 0, 0);
        if (t + 1 < nt_) commit(buf ^ 1);
        __syncthreads();
    }

#pragma unroll
    for (int mt = 0; mt < 4; mt++) {
#pragma unroll
        for (int r = 0; r < 4; r++) {
            int m = m0 + wm * 64 + mt * 16 + quad * 4 + r;
#pragma unroll
            for (int ntx = 0; ntx < 2; ntx++) {
                int col = n0 + wn * 32 + ntx * 16 + l15;
                float v = acc[mt][ntx][r];
                if (BIAS) v += bias[col];
                C[(size_t)m * N + col] = v;
            }
        }
    }
}

// ---------------------------------------------------------------- fused QKV MFMA GEMM (f32 weights)
#define MBM 128
#define MBN 64
#define MBK 32
#define LDAS 40

__global__ __launch_bounds__(256) void qkv_k(
    const float* __restrict__ A,          // [BT_][512]
    const float* __restrict__ wq, const float* __restrict__ wk,
    const float* __restrict__ wv,
    float* __restrict__ qo, float* __restrict__ ko, float* __restrict__ vo)
{
    __shared__ __align__(16) __bf16 As[MBM * LDAS];
    __shared__ __align__(16) __bf16 Bs[MBN * LDAS];

    int n0g = blockIdx.x * MBN;
    int which = n0g >> 9;
    int n0 = n0g & 511;
    const float* Bp = (which == 0) ? wq : (which == 1) ? wk : wv;
    float* Cp = (which == 0) ? qo : (which == 1) ? ko : vo;
    int m0 = blockIdx.y * MBM;

    int tid = threadIdx.x;
    int arow = tid >> 1, ahalf = tid & 1;
    const float* aptr = A + (size_t)(m0 + arow) * D_ + ahalf * 16;
    int asw = (arow >> 3) & 3;
    int bn = tid & 63, bkc = tid >> 6;
    int bcs = bkc ^ ((bn >> 3) & 3);

    int lane = tid & 63, wid = tid >> 6;
    int wm = wid & 1, wn = wid >> 1;
    int l15 = lane & 15, quad = lane >> 4;

    int aoff[4], boff[2];
#pragma unroll
    for (int mt = 0; mt < 4; mt++) {
        int m = wm * 64 + mt * 16 + l15;
        aoff[mt] = m * LDAS + (quad ^ ((m >> 3) & 3)) * 8;
    }
#pragma unroll
    for (int nt = 0; nt < 2; nt++) {
        int n = wn * 32 + nt * 16 + l15;
        boff[nt] = n * LDAS + (quad ^ ((n >> 3) & 3)) * 8;
    }

    f32x4 acc[4][2];
#pragma unroll
    for (int mt = 0; mt < 4; mt++)
#pragma unroll
        for (int nt = 0; nt < 2; nt++)
#pragma unroll
            for (int r = 0; r < 4; r++) acc[mt][nt][r] = 0.f;

    for (int k0 = 0; k0 < D_; k0 += MBK) {
#pragma unroll
        for (int cc = 0; cc < 2; cc++) {
            float4 f0 = *(const float4*)(aptr + k0 + cc * 8);
            float4 f1 = *(const float4*)(aptr + k0 + cc * 8 + 4);
            uint4 pk = make_uint4(pk2(f0.x, f0.y), pk2(f0.z, f0.w),
                                  pk2(f1.x, f1.y), pk2(f1.z, f1.w));
            int cs = (ahalf * 2 + cc) ^ asw;
            *(uint4*)&As[arow * LDAS + cs * 8] = pk;
        }
        {
            float f[8];
            int kk = k0 + bkc * 8;
#pragma unroll
            for (int i = 0; i < 8; i++)
                f[i] = Bp[(size_t)(kk + i) * D_ + n0 + bn];
            uint4 pk = make_uint4(pk2(f[0], f[1]), pk2(f[2], f[3]),
                                  pk2(f[4], f[5]), pk2(f[6], f[7]));
            *(uint4*)&Bs[bn * LDAS + bcs * 8] = pk;
        }
        __syncthreads();
        bf16x8 af[4], bfm[2];
#pragma unroll
        for (int mt = 0; mt < 4; mt++) af[mt] = *(const bf16x8*)&As[aoff[mt]];
#pragma unroll
        for (int nt = 0; nt < 2; nt++) bfm[nt] = *(const bf16x8*)&Bs[boff[nt]];
#pragma unroll
        for (int mt = 0; mt < 4; mt++)
#pragma unroll
            for (int nt = 0; nt < 2; nt++)
                acc[mt][nt] = __builtin_amdgcn_mfma_f32_16x16x32_bf16(
                    af[mt], bfm[nt], acc[mt][nt], 0, 0, 0);
        __syncthreads();
    }

#pragma unroll
    for (int mt = 0; mt < 4; mt++) {
#pragma unroll
        for (int r = 0; r < 4; r++) {
            int mi = wm * 64 + mt * 16 + quad * 4 + r;
            int m = m0 + mi;
#pragma unroll
            for (int nt = 0; nt < 2; nt++) {
                int col = n0 + wn * 32 + nt * 16 + l15;
                Cp[(size_t)m * D_ + col] = acc[mt][nt][r];
            }
        }
    }
}

// ---------------------------------------------------------------- small ops
__global__ void bucketall_k(const int* __restrict__ eidA, int* __restrict__ sortedA,
                            int* __restrict__ segA)
{
    __shared__ int cnt[E_]; __shared__ int cur[E_];
    int l = blockIdx.x;
    const int* eid = eidA + l * BT_;
    int* sorted = sortedA + l * BT_;
    int* seg = segA + l * 8;
    int tid = threadIdx.x;
    if (tid < E_) cnt[tid] = 0;
    __syncthreads();
    for (int t = tid; t < BT_; t += 256) atomicAdd(&cnt[eid[t]], 1);
    __syncthreads();
    if (tid == 0) {
        int o = 0;
        for (int e = 0; e < E_; e++) { seg[e] = o; cur[e] = o; o += cnt[e]; }
        seg[E_] = o;
    }
    __syncthreads();
    for (int t = tid; t < BT_; t += 256) {
        int pos = atomicAdd(&cur[eid[t]], 1);
        sorted[pos] = t;
    }
}

// fsmn + optional skip + optional fused positional encoding
__global__ void fsmn_k(const float* __restrict__ p, const float* __restrict__ fb,
                       const float* __restrict__ fa, float* __restrict__ cur,
                       int skip, int pe)
{
    int idx = blockIdx.x * 256 + threadIdx.x;
    int d = idx & 511;
    int t = (idx >> 9) & 511;
    float m = p[idx];
#pragma unroll
    for (int k = 0; k < 4; k++) {
        int tt = t - 2 * (k + 1);
        if (tt >= 0) m += fb[k * D_ + d] * p[idx - D_ * 2 * (k + 1)];
    }
    if (t + 1 < T_) m += fa[d] * p[idx + D_];
    if (skip) m += cur[idx];
    if (pe) {
        float div = expf((float)(d & ~1) * (-9.210340371976184f / (float)D_));
        float ang = (float)t * div;
        m += (d & 1) ? cosf(ang) : sinf(ang);
    }
    cur[idx] = m;
}

// ---------------------------------------------------------------- attention v2 (mem rows direct from mk/mv)
#define QR 16
__global__ __launch_bounds__(256) void attn_k(
    const float* __restrict__ q, const float* __restrict__ kbuf,
    const float* __restrict__ vbuf, const float* __restrict__ mk,
    const float* __restrict__ mv, const int* __restrict__ seq_len,
    float* __restrict__ attno)
{
    __shared__ float kv[64 * 68];     // score: [d][key]; PV: [key][d]
    __shared__ float qs[QR][68];
    __shared__ float sc[QR][584];     // 576 + 8 pad
    int b = blockIdx.z, h = blockIdx.y, t0 = blockIdx.x * QR;
    int tid = threadIdx.x, w = tid >> 6, lane = tid & 63;
    int r0 = w * 4;
#pragma unroll
    for (int i = 0; i < 4; i++) {
        int idx = tid + 256 * i;
        int r = idx >> 6, d = idx & 63;
        qs[r][d] = q[((size_t)(b * T_) + t0 + r) * D_ + h * DH_ + d] * 0.125f;
    }
    int sl = seq_len[b];
    int ntv = (sl + 63) >> 6;         // valid T-tiles; memory tile always valid
    int kg = lane & 15, quad = lane >> 4;
    int myrow = r0 + quad;

    // ---- score phase over valid tiles
    for (int ti = 0; ti <= ntv; ti++) {
        int t = (ti < ntv) ? ti : 8;
        int s0 = t * 64;
        __syncthreads();
        {   // stage K as [d][key] (rows from kbuf or memory keys)
            const float* kp = (t < 8)
                ? kbuf + ((size_t)(b * T_) + s0 + w * 16) * D_ + h * DH_ + lane
                : mk + (size_t)(w * 16) * D_ + h * DH_ + lane;
#pragma unroll
            for (int jj = 0; jj < 4; jj++) {
                float4 kf;
                kf.x = kp[(jj * 4 + 0) * D_];
                kf.y = kp[(jj * 4 + 1) * D_];
                kf.z = kp[(jj * 4 + 2) * D_];
                kf.w = kp[(jj * 4 + 3) * D_];
                *(float4*)&kv[lane * 68 + w * 16 + jj * 4] = kf;
            }
        }
        __syncthreads();
        float a0 = 0, a1 = 0, a2 = 0, a3 = 0;
#pragma unroll 8
        for (int d = 0; d < 64; d++) {
            float4 kf = *(const float4*)&kv[d * 68 + kg * 4];
            float qv = qs[myrow][d];
            a0 = fmaf(qv, kf.x, a0);
            a1 = fmaf(qv, kf.y, a1);
            a2 = fmaf(qv, kf.z, a2);
            a3 = fmaf(qv, kf.w, a3);
        }
        int sb = s0 + kg * 4;
        float4 o;
        o.x = (sb + 0 >= T_ || sb + 0 < sl) ? a0 : -1e9f;
        o.y = (sb + 1 >= T_ || sb + 1 < sl) ? a1 : -1e9f;
        o.z = (sb + 2 >= T_ || sb + 2 < sl) ? a2 : -1e9f;
        o.w = (sb + 3 >= T_ || sb + 3 < sl) ? a3 : -1e9f;
        *(float4*)&sc[myrow][s0 + kg * 4] = o;
    }
    __syncthreads();

    // ---- softmax (wave-private rows, valid tiles only)
    float inv[4];
#pragma unroll
    for (int r = 0; r < 4; r++) {
        float mx = -1e30f;
        for (int ti = 0; ti <= ntv; ti++) {
            int s0 = ((ti < ntv) ? ti : 8) * 64;
            mx = fmaxf(mx, sc[r0 + r][s0 + lane]);
        }
        for (int off = 32; off; off >>= 1) mx = fmaxf(mx, __shfl_xor(mx, off));
        float sum = 0.f;
        for (int ti = 0; ti <= ntv; ti++) {
            int s0 = ((ti < ntv) ? ti : 8) * 64;
            float e2 = expf(sc[r0 + r][s0 + lane] - mx);
            sc[r0 + r][s0 + lane] = e2; sum += e2;
        }
        for (int off = 32; off; off >>= 1) sum += __shfl_xor(sum, off);
        inv[r] = 1.f / sum;
    }

    // ---- PV phase (lane = d)
    float o0 = 0, o1 = 0, o2 = 0, o3 = 0;
    for (int ti = 0; ti <= ntv; ti++) {
        int t = (ti < ntv) ? ti : 8;
        int s0 = t * 64;
        __syncthreads();
#pragma unroll
        for (int i = 0; i < 16; i++) {
            int idx = tid + 256 * i;
            int key = idx >> 6, d = idx & 63;
            const float* vp = (t < 8)
                ? vbuf + ((size_t)(b * T_) + s0 + key) * D_ + h * DH_ + d
                : mv + (size_t)key * D_ + h * DH_ + d;
            kv[key * 68 + d] = *vp;
        }
        __syncthreads();
#pragma unroll 4
        for (int g = 0; g < 16; g++) {
            float4 p0 = *(const float4*)&sc[r0 + 0][s0 + g * 4];
            float4 p1 = *(const float4*)&sc[r0 + 1][s0 + g * 4];
            float4 p2 = *(const float4*)&sc[r0 + 2][s0 + g * 4];
            float4 p3 = *(const float4*)&sc[r0 + 3][s0 + g * 4];
            float v0 = kv[(g * 4 + 0) * 68 + lane];
            float v1 = kv[(g * 4 + 1) * 68 + lane];
            float v2 = kv[(g * 4 + 2) * 68 + lane];
            float v3 = kv[(g * 4 + 3) * 68 + lane];
            o0 += p0.x * v0 + p0.y * v1 + p0.z * v2 + p0.w * v3;
            o1 += p1.x * v0 + p1.y * v1 + p1.z * v2 + p1.w * v3;
            o2 += p2.x * v0 + p2.y * v1 + p2.z * v2 + p2.w * v3;
            o3 += p3.x * v0 + p3.y * v1 + p3.z * v2 + p3.w * v3;
        }
    }
    size_t base = ((size_t)(b * T_) + t0 + r0) * D_ + h * DH_ + lane;
    attno[base + 0 * D_] = o0 * inv[0];
    attno[base + 1 * D_] = o1 * inv[1];
    attno[base + 2 * D_] = o2 * inv[2];
    attno[base + 3 * D_] = o3 * inv[3];
}

__global__ void ln_k(const float* __restrict__ o, const float* __restrict__ g,
                     const float* __restrict__ bb, float* __restrict__ cur)
{
    int w = threadIdx.x >> 6, lane = threadIdx.x & 63;
    size_t row = (size_t)(blockIdx.x * 4 + w);
    float v[8]; float s = 0.f;
#pragma unroll
    for (int i = 0; i < 8; i++) {
        int d = lane + 64 * i;
        v[i] = cur[row * D_ + d] + o[row * D_ + d];
        s += v[i];
    }
    for (int off = 32; off; off >>= 1) s += __shfl_xor(s, off);
    float mu = s * (1.f / D_);
    float vs = 0.f;
#pragma unroll
    for (int i = 0; i < 8; i++) { float dd = v[i] - mu; vs += dd * dd; }
    for (int off = 32; off; off >>= 1) vs += __shfl_xor(vs, off);
    float rstd = rsqrtf(vs * (1.f / D_) + 1e-5f);
#pragma unroll
    for (int i = 0; i < 8; i++) {
        int d = lane + 64 * i;
        cur[row * D_ + d] = (v[i] - mu) * rstd * g[d] + bb[d];
    }
}

// reduce impPart[RBLK_][32] -> imp[8][4], then cv^2 sum (deterministic)
__global__ __launch_bounds__(256) void aux_k(const float* __restrict__ impPart,
                                             float* __restrict__ outp)
{
    __shared__ float red[8][32];
    __shared__ float imp[32];
    int tid = threadIdx.x;
    int c = tid & 31, p = tid >> 5;
    float s = 0.f;
    for (int b = p; b < RBLK_; b += 8) s += impPart[(size_t)b * 32 + c];
    red[p][c] = s;
    __syncthreads();
    if (tid < 32) {
        float t = 0.f;
#pragma unroll
        for (int i = 0; i < 8; i++) t += red[i][tid];
        imp[tid] = t;
    }
    __syncthreads();
    if (tid == 0) {
        float total = 0.f;
        for (int l = 0; l < 8; l++) {
            const float* ip = imp + l * 4;
            float m = (ip[0] + ip[1] + ip[2] + ip[3]) * 0.25f;
            float var = 0.f;
            for (int e = 0; e < 4; e++) { float d = ip[e] - m; var += d * d; }
            var *= 0.25f;
            total += var / (m * m + 1e-9f);
        }
        *outp = total;
    }
}

// ============================================================================
extern "C" void kernel_launch(void* const* d_in, const int* in_sizes, int n_in,
                              void* d_out, int out_size, void* d_ws, size_t ws_size,
                              hipStream_t stream)
{
    (void)in_sizes; (void)n_in; (void)out_size; (void)ws_size;
    const float* x        = (const float*)d_in[0];
    const int*   seqlen   = (const int*)d_in[1];
    const float* emb_w1   = (const float*)d_in[2];
    const float* emb_b1   = (const float*)d_in[3];
    const float* emb_w2   = (const float*)d_in[4];
    const float* emb_wo   = (const float*)d_in[5];
    const float* f0_w1    = (const float*)d_in[6];
    const float* f0_b1    = (const float*)d_in[7];
    const float* f0_w2    = (const float*)d_in[8];
    const float* f0_router= (const float*)d_in[9];
    const float* f0_fb    = (const float*)d_in[10];
    const float* f0_fa    = (const float*)d_in[11];
    const float* f_w1     = (const float*)d_in[12];
    const float* f_b1     = (const float*)d_in[13];
    const float* f_w2     = (const float*)d_in[14];
    const float* f_router = (const float*)d_in[15];
    const float* f_fb     = (const float*)d_in[16];
    const float* f_fa     = (const float*)d_in[17];
    const float* attn_wq  = (const float*)d_in[18];
    const float* attn_wk  = (const float*)d_in[19];
    const float* attn_wv  = (const float*)d_in[20];
    const float* attn_wo  = (const float*)d_in[21];
    const float* attn_mk  = (const float*)d_in[22];
    const float* attn_mv  = (const float*)d_in[23];
    const float* ln_g     = (const float*)d_in[24];
    const float* ln_b     = (const float*)d_in[25];
    const float* out_w    = (const float*)d_in[26];
    const float* out_b    = (const float*)d_in[27];

    float* out0 = (float*)d_out;
    float* out1 = out0 + (size_t)BT_ * OUT_;
    float* out2 = out1 + (size_t)BT_ * OUT_;

    float* fws = (float*)d_ws;
    size_t o = 0;
    float* embedF = fws + o; o += (size_t)BT_ * D_;       // 1M floats
    float* curB   = fws + o; o += (size_t)BT_ * D_;       // 1M
    float* hbuf   = fws + o; o += (size_t)BT_ * HID_;     // 2M (h | hbufh | attno+tmpo)
    float* pbuf   = fws + o; o += (size_t)BT_ * D_;       // 1M (also qbuf)
    float* kbuf   = fws + o; o += (size_t)BT_ * D_;       // 1M
    float* vbuf   = fws + o; o += (size_t)BT_ * D_;       // 1M
    float* gatev  = fws + o; o += (size_t)8 * BT_;
    float* impPart= fws + o; o += (size_t)RBLK_ * 32;
    float* R2     = fws + o; o += (size_t)8 * 1024 * 4;
    int* eid     = (int*)(fws + o); o += (size_t)8 * BT_;
    int* sortedA = (int*)(fws + o); o += (size_t)8 * BT_;
    int* segA    = (int*)(fws + o); o += 64;
    __bf16* hbufh = (__bf16*)hbuf;     // expert hidden bf16 [2048][1024] (loop only)
    float* qbuf  = pbuf;
    float* attno = hbuf;               // attn phase only
    float* tmpo  = hbuf + (size_t)BT_ * D_;

    // h = relu(x@emb_w1+b1) — exact f32 (feeds routing)
    gemm80_k<<<dim3(HID_ / 64, BT_ / 64, 1), 256, 0, stream>>>(x, emb_w1, emb_b1, hbuf);
    // R2[l] = emb_w2 @ router_l in f64
    wr2_k<<<256, 256, 0, stream>>>(emb_w2, f0_router, f_router, R2);
    routerall_k<<<RBLK_, 256, 0, stream>>>(hbuf, R2, seqlen, eid, gatev, impPart);
    bucketall_k<<<8, 256, 0, stream>>>(eid, sortedA, segA);
    // embed head (in-kernel bf16 convert of weights)
    dgemm_k<false><<<dim3(D_ / 64, BT_ / 128, 1), 256, 0, stream>>>(
        hbuf, emb_w2, nullptr, embedF, D_, HID_);
    dgemm_k<false><<<dim3(OUT_ / 64, BT_ / 128, 1), 256, 0, stream>>>(
        embedF, emb_wo, nullptr, out1, OUT_, D_);
    // hbuf (h) dead from here.

    for (int l = 0; l < 8; l++) {
        const float* w1  = (l == 0) ? f0_w1 : f_w1 + (size_t)(l-1) * E_ * D_ * HID_;
        const float* b1p = (l == 0) ? f0_b1 : f_b1 + (size_t)(l-1) * E_ * HID_;
        const float* w2  = (l == 0) ? f0_w2 : f_w2 + (size_t)(l-1) * E_ * HID_ * D_;
        const float* fbp = (l == 0) ? f0_fb : f_fb + (size_t)(l-1) * 4 * D_;
        const float* fap = (l == 0) ? f0_fa : f_fa + (size_t)(l-1) * 1 * D_;
        const float* Ain = (l == 0) ? x : curB;
        int lda  = (l == 0) ? IN_ : D_;
        int Ks   = (l == 0) ? IN_ : D_;
        int Kp   = (l == 0) ? 128 : 512;
        const int* seg = segA + l * 8;
        const int* sorted = sortedA + l * BT_;

        egemm_k<true><<<dim3(HID_/64, BT_/128, E_), 256, 0, stream>>>(
            Ain, lda, Ks, nullptr, w1, b1p, hbufh, nullptr, HID_, Kp,
            seg, sorted, nullptr);
        egemm_k<false><<<dim3(D_/64, BT_/128, E_), 256, 0, stream>>>(
            nullptr, 0, HID_, hbufh, w2, nullptr, nullptr, pbuf, D_, HID_,
            seg, sorted, gatev + l * BT_);
        fsmn_k<<<BT_*D_/256, 256, 0, stream>>>(pbuf, fbp, fap, curB,
                                               (l > 0) ? 1 : 0, (l == 3) ? 1 : 0);

        if (l == 3 || l == 7) {
            int ab = (l == 3) ? 0 : 1;
            const float* wq = attn_wq + (size_t)ab * D_ * D_;
            const float* wk = attn_wk + (size_t)ab * D_ * D_;
            const float* wv = attn_wv + (size_t)ab * D_ * D_;
            const float* wo = attn_wo + (size_t)ab * D_ * D_;
            const float* mk = attn_mk + (size_t)ab * M_ * D_;
            const float* mv = attn_mv + (size_t)ab * M_ * D_;
            const float* g  = ln_g + (size_t)ab * D_;
            const float* bb = ln_b + (size_t)ab * D_;

            qkv_k<<<dim3(3 * D_ / MBN, BT_ / MBM, 1), 256, 0, stream>>>(
                curB, wq, wk, wv, qbuf, kbuf, vbuf);
            attn_k<<<dim3(T_/QR, H_, B_), 256, 0, stream>>>(
                qbuf, kbuf, vbuf, mk, mv, seqlen, attno);
            dgemm_k<false><<<dim3(D_ / 64, BT_ / 128, 1), 256, 0, stream>>>(
                attno, wo, nullptr, tmpo, D_, D_);
            ln_k<<<BT_/4, 256, 0, stream>>>(tmpo, g, bb, curB);
        }
    }

    dgemm_k<true><<<dim3(OUT_ / 64, BT_ / 128, 1), 256, 0, stream>>>(
        curB, out_w, out_b, out0, OUT_, D_);
    aux_k<<<1, 256, 0, stream>>>(impPart, out2);
}

// Round 7
// 1383.869 us; speedup vs baseline: 1.7587x; 1.7587x over previous
//
#include <hip/hip_runtime.h>
#include <hip/hip_bf16.h>

// ============================================================================
// Net_72662256713812 — round 10: revert expert path to r8 (prep-kernel reuse),
// keep r9's safe fusions, fuse prep into one launch.
//  - r9 postmortem: in-kernel weight-convert/gather killed 16x reuse ->
//    egemm 148us (HBM 192GB/s, 21.5MB fetch). Pre-convert + pre-gather
//    restored; prep fused into ONE prep_k launch per layer.
//  - kept from r9: fsmn+PE fusion, attn mk/mv direct (no fillmem), plain
//    [BT][D] K/V, f32 qkv weights. wo-GEMM uses f32 B (1MB, L2-resident).
//  - dense N=4096 GEMMs keep bf16-B pre-convert (f32 B doesn't fit XCD L2).
//  - 51 launches/forward vs r8's 78, r8 kernel speeds. Rounding identical.
// ============================================================================

typedef __bf16 bf16x8 __attribute__((ext_vector_type(8)));
typedef float f32x4 __attribute__((ext_vector_type(4)));

#define B_ 4
#define T_ 512
#define IN_ 80
#define OUT_ 4096
#define D_ 512
#define HID_ 1024
#define E_ 4
#define H_ 8
#define DH_ 64
#define M_ 64
#define BT_ (B_ * T_)        // 2048
#define TKV_ (T_ + M_)       // 576
#define RBLK_ (BT_ / 4)      // 512 router blocks

__device__ __forceinline__ unsigned pk2(float a, float b) {
    unsigned short ua = __builtin_bit_cast(unsigned short, (__bf16)a);
    unsigned short ub = __builtin_bit_cast(unsigned short, (__bf16)b);
    return (unsigned)ua | ((unsigned)ub << 16);
}
__device__ __forceinline__ unsigned pkh2(__bf16 a, __bf16 b) {
    unsigned short ua = __builtin_bit_cast(unsigned short, a);
    unsigned short ub = __builtin_bit_cast(unsigned short, b);
    return (unsigned)ua | ((unsigned)ub << 16);
}

// ---------------------------------------------------------------- embed w1 (f32, K=80)
__global__ __launch_bounds__(256) void gemm80_k(
    const float* __restrict__ A,    // [BT_][80]
    const float* __restrict__ Bw,   // [80][1024]
    const float* __restrict__ bias, // [1024]
    float* __restrict__ C)          // [BT_][1024]
{
    __shared__ float As[80][68];   // [k][m]
    __shared__ float Bs[80][68];   // [k][n]
    int m0 = blockIdx.y * 64, n0 = blockIdx.x * 64;
    int tid = threadIdx.x;
#pragma unroll
    for (int i = 0; i < 5; i++) {
        int idx = tid + 256 * i;          // 0..1279
        int m = idx / 20, c = idx % 20;
        float4 f = *(const float4*)&A[(size_t)(m0 + m) * 80 + c * 4];
        As[c * 4 + 0][m] = f.x; As[c * 4 + 1][m] = f.y;
        As[c * 4 + 2][m] = f.z; As[c * 4 + 3][m] = f.w;
    }
#pragma unroll
    for (int i = 0; i < 5; i++) {
        int idx = tid + 256 * i;
        int k = idx / 16, c = idx % 16;
        float4 f = *(const float4*)&Bw[(size_t)k * 1024 + n0 + c * 4];
        *(float4*)&Bs[k][c * 4] = f;
    }
    __syncthreads();
    int tx = tid & 15, ty = tid >> 4;
    float acc[4][4];
#pragma unroll
    for (int j = 0; j < 4; j++)
#pragma unroll
        for (int i = 0; i < 4; i++) acc[j][i] = 0.f;
#pragma unroll 8
    for (int k = 0; k < 80; k++) {
        float4 a = *(const float4*)&As[k][ty * 4];
        float4 b = *(const float4*)&Bs[k][tx * 4];
        float av[4] = {a.x, a.y, a.z, a.w};
        float bv[4] = {b.x, b.y, b.z, b.w};
#pragma unroll
        for (int j = 0; j < 4; j++)
#pragma unroll
            for (int i = 0; i < 4; i++) acc[j][i] += av[j] * bv[i];
    }
#pragma unroll
    for (int j = 0; j < 4; j++) {
        size_t row = (size_t)(m0 + ty * 4 + j);
        float4 o;
        o.x = fmaxf(acc[j][0] + bias[n0 + tx * 4 + 0], 0.f);
        o.y = fmaxf(acc[j][1] + bias[n0 + tx * 4 + 1], 0.f);
        o.z = fmaxf(acc[j][2] + bias[n0 + tx * 4 + 2], 0.f);
        o.w = fmaxf(acc[j][3] + bias[n0 + tx * 4 + 3], 0.f);
        *(float4*)&C[row * 1024 + n0 + tx * 4] = o;
    }
}

// ---------------------------------------------------------------- R2 = emb_w2 @ router_l (f64 accum)
__global__ void wr2_k(const float* __restrict__ w2,   // [1024][512]
                      const float* __restrict__ r0,   // [512][4]
                      const float* __restrict__ rl,   // [7][512][4]
                      float* __restrict__ R2)         // [8][1024][4]
{
    int wv = threadIdx.x >> 6, lane = threadIdx.x & 63;
    int h = blockIdx.x * 4 + wv;
    const float* wrow = w2 + (size_t)h * 512;
    float w[8];
#pragma unroll
    for (int i = 0; i < 8; i++) w[i] = wrow[lane + 64 * i];
    for (int l = 0; l < 8; l++) {
        const float* rp = (l == 0) ? r0 : rl + (size_t)(l - 1) * 2048;
        double a0 = 0, a1 = 0, a2 = 0, a3 = 0;
#pragma unroll
        for (int i = 0; i < 8; i++) {
            int d = lane + 64 * i;
            float4 r = *(const float4*)&rp[d * 4];
            a0 += (double)w[i] * (double)r.x;
            a1 += (double)w[i] * (double)r.y;
            a2 += (double)w[i] * (double)r.z;
            a3 += (double)w[i] * (double)r.w;
        }
        for (int off = 32; off; off >>= 1) {
            a0 += __shfl_xor(a0, off); a1 += __shfl_xor(a1, off);
            a2 += __shfl_xor(a2, off); a3 += __shfl_xor(a3, off);
        }
        if (lane == 0) {
            float4 o = make_float4((float)a0, (float)a1, (float)a2, (float)a3);
            *(float4*)&R2[((size_t)l * 1024 + h) * 4] = o;
        }
    }
}

// ---------------------------------------------------------------- all-layers routing from h
__global__ __launch_bounds__(256) void routerall_k(
    const float* __restrict__ h,    // [BT_][1024]
    const float* __restrict__ R2,   // [8][1024][4]
    const int* __restrict__ seq_len,
    int* __restrict__ eid,          // [8][BT_]
    float* __restrict__ gatev,      // [8][BT_]
    float* __restrict__ impPart)    // [RBLK_][32]
{
    __shared__ float impLoc[4][32];
    int wv = threadIdx.x >> 6, lane = threadIdx.x & 63;
    int tok = blockIdx.x * 4 + wv;
    const float* hr = h + (size_t)tok * 1024;
    float acc[8][4];
#pragma unroll
    for (int l = 0; l < 8; l++)
#pragma unroll
        for (int e = 0; e < 4; e++) acc[l][e] = 0.f;
    for (int i = 0; i < 16; i++) {
        int d = lane + 64 * i;
        float hv = hr[d];
#pragma unroll
        for (int l = 0; l < 8; l++) {
            float4 r = *(const float4*)&R2[((size_t)l * 1024 + d) * 4];
            acc[l][0] += hv * r.x; acc[l][1] += hv * r.y;
            acc[l][2] += hv * r.z; acc[l][3] += hv * r.w;
        }
    }
    for (int off = 32; off; off >>= 1) {
#pragma unroll
        for (int l = 0; l < 8; l++)
#pragma unroll
            for (int e = 0; e < 4; e++) acc[l][e] += __shfl_xor(acc[l][e], off);
    }
    if (lane == 0) {
        int b = tok >> 9, t = tok & 511;
        bool valid = t < seq_len[b];
        for (int l = 0; l < 8; l++) {
            float lg[4] = {acc[l][0], acc[l][1], acc[l][2], acc[l][3]};
            float mx = fmaxf(fmaxf(lg[0], lg[1]), fmaxf(lg[2], lg[3]));
            float g[4], s = 0.f;
            for (int e = 0; e < 4; e++) { g[e] = expf(lg[e] - mx); s += g[e]; }
            float inv = 1.f / s;
            int am = 0; float bv = g[0];
            for (int e = 1; e < 4; e++) if (g[e] > bv) { bv = g[e]; am = e; }
            eid[l * BT_ + tok] = am;
            gatev[l * BT_ + tok] = bv * inv;
            for (int e = 0; e < 4; e++)
                impLoc[wv][l * 4 + e] = valid ? g[e] * inv : 0.f;
        }
    }
    __syncthreads();
    int tid = threadIdx.x;
    if (tid < 32) {
        float s = impLoc[0][tid] + impLoc[1][tid] + impLoc[2][tid] + impLoc[3][tid];
        impPart[(size_t)blockIdx.x * 32 + tid] = s;
    }
}

// ---------------------------------------------------------------- convert / gather bodies
__device__ __forceinline__ void cvt_body(const float* __restrict__ src,
                                         __bf16* __restrict__ dst,
                                         int idx, int nsh, int kpsh, int Ksrc)
{
    int cprsh = nsh - 3;
    int row = idx >> cprsh;                      // e*Kpad + k
    int chunk = idx & ((1 << cprsh) - 1);
    int e = row >> kpsh, k = row & ((1 << kpsh) - 1);
    int n = chunk * 8;
    uint4 pk;
    if (k < Ksrc) {
        const float* sp = src + (((size_t)e * Ksrc + k) << nsh) + n;
        float4 f0 = *(const float4*)sp;
        float4 f1 = *(const float4*)(sp + 4);
        pk = make_uint4(pk2(f0.x, f0.y), pk2(f0.z, f0.w),
                        pk2(f1.x, f1.y), pk2(f1.z, f1.w));
    } else pk = make_uint4(0, 0, 0, 0);
    *(uint4*)&dst[(((size_t)row) << nsh) + n] = pk;
}

__device__ __forceinline__ void gather_body(const float* __restrict__ src, int lda,
                                            const int* __restrict__ sorted,
                                            __bf16* __restrict__ dst,
                                            int idx, int kpsh, int Ksrc)
{
    int cprsh = kpsh - 3;
    int row = idx >> cprsh;
    int chunk = idx & ((1 << cprsh) - 1);
    int k0 = chunk * 8;
    uint4 pk;
    if (k0 < Ksrc) {
        const float* sp = src + (size_t)sorted[row] * lda + k0;
        float4 f0 = *(const float4*)sp;
        float4 f1 = *(const float4*)(sp + 4);
        pk = make_uint4(pk2(f0.x, f0.y), pk2(f0.z, f0.w),
                        pk2(f1.x, f1.y), pk2(f1.z, f1.w));
    } else pk = make_uint4(0, 0, 0, 0);
    *(uint4*)&dst[((size_t)row << kpsh) + k0] = pk;
}

// standalone convert (pre/post-loop weights)
__global__ void cvtw_k(const float* __restrict__ src, __bf16* __restrict__ dst,
                       int nsh, int kpsh, int Ksrc)
{
    cvt_body(src, dst, blockIdx.x * 256 + threadIdx.x, nsh, kpsh, Ksrc);
}

// fused per-layer prep: w1 cvt | w2 cvt | A gather (one launch)
__global__ void prep_k(const float* __restrict__ w1, const float* __restrict__ w2,
                       const float* __restrict__ Ain, int lda,
                       const int* __restrict__ sorted,
                       __bf16* __restrict__ w1h, __bf16* __restrict__ w2h,
                       __bf16* __restrict__ Ag,
                       int kpsh, int Ks, int nb1, int nb2)
{
    int bx = blockIdx.x;
    if (bx < nb1) {
        cvt_body(w1, w1h, bx * 256 + threadIdx.x, 10, kpsh, Ks);
    } else if (bx < nb1 + nb2) {
        cvt_body(w2, w2h, (bx - nb1) * 256 + threadIdx.x, 9, 10, HID_);
    } else {
        gather_body(Ain, lda, sorted, Ag, (bx - nb1 - nb2) * 256 + threadIdx.x,
                    kpsh, Ks);
    }
}

// ---------------------------------------------------------------- pipelined expert GEMM (bf16 in; r8 structure)
template<bool W1OUT>
__global__ __launch_bounds__(256) void egemm_k(
    const __bf16* __restrict__ Ag, const __bf16* __restrict__ Bh,
    const float* __restrict__ bias,
    __bf16* __restrict__ Cb, float* __restrict__ Cf,
    int N, int Kpad,
    const int* __restrict__ seg, const int* __restrict__ sorted,
    const float* __restrict__ scale)
{
    __shared__ __align__(16) __bf16 As[2][128 * 64];
    __shared__ __align__(16) __bf16 Bs[2][64 * 64];

    int e = blockIdx.z;
    int row0 = seg[e], cnt = seg[e + 1] - row0;
    int m0 = blockIdx.y * 128;
    if (m0 >= cnt) return;
    int n0 = blockIdx.x * 64;
    const __bf16* Bp = Bh + (size_t)e * Kpad * N;

    int tid = threadIdx.x;
    int arow = tid >> 1, ahalf = tid & 1;
    int mclamp = min(m0 + arow, cnt - 1);
    const __bf16* aptr = Ag + (size_t)(row0 + mclamp) * Kpad + ahalf * 32;
    int asb = arow * 64;
    int ac0 = ahalf * 4;
    int arx = arow & 7;
    int bn = tid & 63, bkc = tid >> 6;
    const __bf16* bptr = Bp + n0 + bn;
    int bsb = bn * 64;
    int brx = bn & 7;

    int lane = tid & 63, wid = tid >> 6;
    int wm = wid & 1, wn = wid >> 1;
    int l15 = lane & 15, quad = lane >> 4;

    int aoff[4][2], boff[2][2];
#pragma unroll
    for (int mt = 0; mt < 4; mt++) {
        int m = wm * 64 + mt * 16 + l15;
#pragma unroll
        for (int s = 0; s < 2; s++)
            aoff[mt][s] = m * 64 + (((s * 4 + quad) ^ (m & 7)) * 8);
    }
#pragma unroll
    for (int nt = 0; nt < 2; nt++) {
        int n = wn * 32 + nt * 16 + l15;
#pragma unroll
        for (int s = 0; s < 2; s++)
            boff[nt][s] = n * 64 + (((s * 4 + quad) ^ (n & 7)) * 8);
    }

    f32x4 acc[4][2];
#pragma unroll
    for (int mt = 0; mt < 4; mt++)
#pragma unroll
        for (int nt = 0; nt < 2; nt++)
#pragma unroll
            for (int r = 0; r < 4; r++) acc[mt][nt][r] = 0.f;

    uint4 rA[4]; unsigned rB[8];
    auto stage = [&](int k0) {
#pragma unroll
        for (int j = 0; j < 4; j++) rA[j] = *(const uint4*)(aptr + k0 + j * 8);
#pragma unroll
        for (int c = 0; c < 2; c++) {
            int kk = k0 + (bkc * 2 + c) * 8;
#pragma unroll
            for (int i = 0; i < 4; i++)
                rB[c * 4 + i] = pkh2(bptr[(size_t)(kk + 2 * i) * N],
                                     bptr[(size_t)(kk + 2 * i + 1) * N]);
        }
    };
    auto commit = [&](int buf) {
#pragma unroll
        for (int j = 0; j < 4; j++)
            *(uint4*)&As[buf][asb + (((ac0 + j) ^ arx) * 8)] = rA[j];
#pragma unroll
        for (int c = 0; c < 2; c++)
            *(uint4*)&Bs[buf][bsb + (((bkc * 2 + c) ^ brx) * 8)] =
                make_uint4(rB[c * 4 + 0], rB[c * 4 + 1], rB[c * 4 + 2], rB[c * 4 + 3]);
    };

    stage(0); commit(0); __syncthreads();
    int nt_ = Kpad >> 6;
    for (int t = 0; t < nt_; t++) {
        int buf = t & 1;
        if (t + 1 < nt_) stage((t + 1) << 6);
        bf16x8 af[4][2], bfr[2][2];
#pragma unroll
        for (int mt = 0; mt < 4; mt++)
#pragma unroll
            for (int s = 0; s < 2; s++)
                af[mt][s] = *(const bf16x8*)&As[buf][aoff[mt][s]];
#pragma unroll
        for (int ntx = 0; ntx < 2; ntx++)
#pragma unroll
            for (int s = 0; s < 2; s++)
                bfr[ntx][s] = *(const bf16x8*)&Bs[buf][boff[ntx][s]];
#pragma unroll
        for (int mt = 0; mt < 4; mt++)
#pragma unroll
            for (int ntx = 0; ntx < 2; ntx++)
#pragma unroll
                for (int s = 0; s < 2; s++)
                    acc[mt][ntx] = __builtin_amdgcn_mfma_f32_16x16x32_bf16(
                        af[mt][s], bfr[ntx][s], acc[mt][ntx], 0, 0, 0);
        if (t + 1 < nt_) commit(buf ^ 1);
        __syncthreads();
    }

#pragma unroll
    for (int mt = 0; mt < 4; mt++) {
#pragma unroll
        for (int r = 0; r < 4; r++) {
            int m = m0 + wm * 64 + mt * 16 + quad * 4 + r;
            if (m >= cnt) continue;
            if (W1OUT) {
                size_t ci = (size_t)(row0 + m);
#pragma unroll
                for (int ntx = 0; ntx < 2; ntx++) {
                    int col = n0 + wn * 32 + ntx * 16 + l15;
                    float v = acc[mt][ntx][r] + bias[e * N + col];
                    Cb[ci * N + col] = (__bf16)fmaxf(v, 0.f);
                }
            } else {
                int tok = sorted[row0 + m];
                float sc = scale[tok];
#pragma unroll
                for (int ntx = 0; ntx < 2; ntx++) {
                    int col = n0 + wn * 32 + ntx * 16 + l15;
                    Cf[(size_t)tok * N + col] = acc[mt][ntx][r] * sc;
                }
            }
        }
    }
}

// ---------------------------------------------------------------- pipelined dense GEMM (A f32; B bf16 or f32)
template<bool BIAS, bool BF16B>
__global__ __launch_bounds__(256) void dgemm_k(
    const float* __restrict__ A,          // [2048][K] f32
    const void* __restrict__ Bv,          // [K][N] bf16 or f32
    const float* __restrict__ bias,
    float* __restrict__ C,                // [2048][N]
    int N, int K)
{
    __shared__ __align__(16) __bf16 As[2][128 * 64];
    __shared__ __align__(16) __bf16 Bs[2][64 * 64];

    int m0 = blockIdx.y * 128, n0 = blockIdx.x * 64;
    int tid = threadIdx.x;
    int arow = tid >> 1, ahalf = tid & 1;
    const float* aptr = A + (size_t)(m0 + arow) * K + ahalf * 32;
    int asb = arow * 64, ac0 = ahalf * 4, arx = arow & 7;
    int bn = tid & 63, bkc = tid >> 6;
    const __bf16* bh = (const __bf16*)Bv;
    const float*  bf = (const float*)Bv;
    int bsb = bn * 64, brx = bn & 7;

    int lane = tid & 63, wid = tid >> 6;
    int wm = wid & 1, wn = wid >> 1;
    int l15 = lane & 15, quad = lane >> 4;

    int aoff[4][2], boff[2][2];
#pragma unroll
    for (int mt = 0; mt < 4; mt++) {
        int m = wm * 64 + mt * 16 + l15;
#pragma unroll
        for (int s = 0; s < 2; s++)
            aoff[mt][s] = m * 64 + (((s * 4 + quad) ^ (m & 7)) * 8);
    }
#pragma unroll
    for (int nt = 0; nt < 2; nt++) {
        int n = wn * 32 + nt * 16 + l15;
#pragma unroll
        for (int s = 0; s < 2; s++)
            boff[nt][s] = n * 64 + (((s * 4 + quad) ^ (n & 7)) * 8);
    }

    f32x4 acc[4][2];
#pragma unroll
    for (int mt = 0; mt < 4; mt++)
#pragma unroll
        for (int nt = 0; nt < 2; nt++)
#pragma unroll
            for (int r = 0; r < 4; r++) acc[mt][nt][r] = 0.f;

    uint4 rA[4]; unsigned rB[8];
    auto stage = [&](int k0) {
#pragma unroll
        for (int j = 0; j < 4; j++) {
            float4 f0 = *(const float4*)(aptr + k0 + j * 8);
            float4 f1 = *(const float4*)(aptr + k0 + j * 8 + 4);
            rA[j] = make_uint4(pk2(f0.x, f0.y), pk2(f0.z, f0.w),
                               pk2(f1.x, f1.y), pk2(f1.z, f1.w));
        }
#pragma unroll
        for (int c = 0; c < 2; c++) {
            int kk = k0 + (bkc * 2 + c) * 8;
#pragma unroll
            for (int i = 0; i < 4; i++) {
                if (BF16B)
                    rB[c * 4 + i] = pkh2(bh[(size_t)(kk + 2 * i) * N + n0 + bn],
                                         bh[(size_t)(kk + 2 * i + 1) * N + n0 + bn]);
                else
                    rB[c * 4 + i] = pk2(bf[(size_t)(kk + 2 * i) * N + n0 + bn],
                                        bf[(size_t)(kk + 2 * i + 1) * N + n0 + bn]);
            }
        }
    };
    auto commit = [&](int buf) {
#pragma unroll
        for (int j = 0; j < 4; j++)
            *(uint4*)&As[buf][asb + (((ac0 + j) ^ arx) * 8)] = rA[j];
#pragma unroll
        for (int c = 0; c < 2; c++)
            *(uint4*)&Bs[buf][bsb + (((bkc * 2 + c) ^ brx) * 8)] =
                make_uint4(rB[c * 4 + 0], rB[c * 4 + 1], rB[c * 4 + 2], rB[c * 4 + 3]);
    };

    stage(0); commit(0); __syncthreads();
    int nt_ = K >> 6;
    for (int t = 0; t < nt_; t++) {
        int buf = t & 1;
        if (t + 1 < nt_) stage((t + 1) << 6);
        bf16x8 af[4][2], bfr[2][2];
#pragma unroll
        for (int mt = 0; mt < 4; mt++)
#pragma unroll
            for (int s = 0; s < 2; s++)
                af[mt][s] = *(const bf16x8*)&As[buf][aoff[mt][s]];
#pragma unroll
        for (int ntx = 0; ntx < 2; ntx++)
#pragma unroll
            for (int s = 0; s < 2; s++)
                bfr[ntx][s] = *(const bf16x8*)&Bs[buf][boff[ntx][s]];
#pragma unroll
        for (int mt = 0; mt < 4; mt++)
#pragma unroll
            for (int ntx = 0; ntx < 2; ntx++)
#pragma unroll
                for (int s = 0; s < 2; s++)
                    acc[mt][ntx] = __builtin_amdgcn_mfma_f32_16x16x32_bf16(
                        af[mt][s], bfr[ntx][s], acc[mt][ntx], 0, 0, 0);
        if (t + 1 < nt_) commit(buf ^ 1);
        __syncthreads();
    }

#pragma unroll
    for (int mt = 0; mt < 4; mt++) {
#pragma unroll
        for (int r = 0; r < 4; r++) {
            int m = m0 + wm * 64 + mt * 16 + quad * 4 + r;
#pragma unroll
            for (int ntx = 0; ntx < 2; ntx++) {
                int col = n0 + wn * 32 + ntx * 16 + l15;
                float v = acc[mt][ntx][r];
                if (BIAS) v += bias[col];
                C[(size_t)m * N + col] = v;
            }
        }
    }
}

// ---------------------------------------------------------------- fused QKV MFMA GEMM (f32 weights)
#define MBM 128
#define MBN 64
#define MBK 32
#define LDAS 40

__global__ __launch_bounds__(256) void qkv_k(
    const float* __restrict__ A,          // [BT_][512]
    const float* __restrict__ wq, const float* __restrict__ wk,
    const float* __restrict__ wv,
    float* __restrict__ qo, float* __restrict__ ko, float* __restrict__ vo)
{
    __shared__ __align__(16) __bf16 As[MBM * LDAS];
    __shared__ __align__(16) __bf16 Bs[MBN * LDAS];

    int n0g = blockIdx.x * MBN;
    int which = n0g >> 9;
    int n0 = n0g & 511;
    const float* Bp = (which == 0) ? wq : (which == 1) ? wk : wv;
    float* Cp = (which == 0) ? qo : (which == 1) ? ko : vo;
    int m0 = blockIdx.y * MBM;

    int tid = threadIdx.x;
    int arow = tid >> 1, ahalf = tid & 1;
    const float* aptr = A + (size_t)(m0 + arow) * D_ + ahalf * 16;
    int asw = (arow >> 3) & 3;
    int bn = tid & 63, bkc = tid >> 6;
    int bcs = bkc ^ ((bn >> 3) & 3);

    int lane = tid & 63, wid = tid >> 6;
    int wm = wid & 1, wn = wid >> 1;
    int l15 = lane & 15, quad = lane >> 4;

    int aoff[4], boff[2];
#pragma unroll
    for (int mt = 0; mt < 4; mt++) {
        int m = wm * 64 + mt * 16 + l15;
        aoff[mt] = m * LDAS + (quad ^ ((m >> 3) & 3)) * 8;
    }
#pragma unroll
    for (int nt = 0; nt < 2; nt++) {
        int n = wn * 32 + nt * 16 + l15;
        boff[nt] = n * LDAS + (quad ^ ((n >> 3) & 3)) * 8;
    }

    f32x4 acc[4][2];
#pragma unroll
    for (int mt = 0; mt < 4; mt++)
#pragma unroll
        for (int nt = 0; nt < 2; nt++)
#pragma unroll
            for (int r = 0; r < 4; r++) acc[mt][nt][r] = 0.f;

    for (int k0 = 0; k0 < D_; k0 += MBK) {
#pragma unroll
        for (int cc = 0; cc < 2; cc++) {
            float4 f0 = *(const float4*)(aptr + k0 + cc * 8);
            float4 f1 = *(const float4*)(aptr + k0 + cc * 8 + 4);
            uint4 pk = make_uint4(pk2(f0.x, f0.y), pk2(f0.z, f0.w),
                                  pk2(f1.x, f1.y), pk2(f1.z, f1.w));
            int cs = (ahalf * 2 + cc) ^ asw;
            *(uint4*)&As[arow * LDAS + cs * 8] = pk;
        }
        {
            float f[8];
            int kk = k0 + bkc * 8;
#pragma unroll
            for (int i = 0; i < 8; i++)
                f[i] = Bp[(size_t)(kk + i) * D_ + n0 + bn];
            uint4 pk = make_uint4(pk2(f[0], f[1]), pk2(f[2], f[3]),
                                  pk2(f[4], f[5]), pk2(f[6], f[7]));
            *(uint4*)&Bs[bn * LDAS + bcs * 8] = pk;
        }
        __syncthreads();
        bf16x8 af[4], bfm[2];
#pragma unroll
        for (int mt = 0; mt < 4; mt++) af[mt] = *(const bf16x8*)&As[aoff[mt]];
#pragma unroll
        for (int nt = 0; nt < 2; nt++) bfm[nt] = *(const bf16x8*)&Bs[boff[nt]];
#pragma unroll
        for (int mt = 0; mt < 4; mt++)
#pragma unroll
            for (int nt = 0; nt < 2; nt++)
                acc[mt][nt] = __builtin_amdgcn_mfma_f32_16x16x32_bf16(
                    af[mt], bfm[nt], acc[mt][nt], 0, 0, 0);
        __syncthreads();
    }

#pragma unroll
    for (int mt = 0; mt < 4; mt++) {
#pragma unroll
        for (int r = 0; r < 4; r++) {
            int mi = wm * 64 + mt * 16 + quad * 4 + r;
            int m = m0 + mi;
#pragma unroll
            for (int nt = 0; nt < 2; nt++) {
                int col = n0 + wn * 32 + nt * 16 + l15;
                Cp[(size_t)m * D_ + col] = acc[mt][nt][r];
            }
        }
    }
}

// ---------------------------------------------------------------- small ops
__global__ void bucketall_k(const int* __restrict__ eidA, int* __restrict__ sortedA,
                            int* __restrict__ segA)
{
    __shared__ int cnt[E_]; __shared__ int cur[E_];
    int l = blockIdx.x;
    const int* eid = eidA + l * BT_;
    int* sorted = sortedA + l * BT_;
    int* seg = segA + l * 8;
    int tid = threadIdx.x;
    if (tid < E_) cnt[tid] = 0;
    __syncthreads();
    for (int t = tid; t < BT_; t += 256) atomicAdd(&cnt[eid[t]], 1);
    __syncthreads();
    if (tid == 0) {
        int o = 0;
        for (int e = 0; e < E_; e++) { seg[e] = o; cur[e] = o; o += cnt[e]; }
        seg[E_] = o;
    }
    __syncthreads();
    for (int t = tid; t < BT_; t += 256) {
        int pos = atomicAdd(&cur[eid[t]], 1);
        sorted[pos] = t;
    }
}

// fsmn + optional skip + optional fused positional encoding
__global__ void fsmn_k(const float* __restrict__ p, const float* __restrict__ fb,
                       const float* __restrict__ fa, float* __restrict__ cur,
                       int skip, int pe)
{
    int idx = blockIdx.x * 256 + threadIdx.x;
    int d = idx & 511;
    int t = (idx >> 9) & 511;
    float m = p[idx];
#pragma unroll
    for (int k = 0; k < 4; k++) {
        int tt = t - 2 * (k + 1);
        if (tt >= 0) m += fb[k * D_ + d] * p[idx - D_ * 2 * (k + 1)];
    }
    if (t + 1 < T_) m += fa[d] * p[idx + D_];
    if (skip) m += cur[idx];
    if (pe) {
        float div = expf((float)(d & ~1) * (-9.210340371976184f / (float)D_));
        float ang = (float)t * div;
        m += (d & 1) ? cosf(ang) : sinf(ang);
    }
    cur[idx] = m;
}

// ---------------------------------------------------------------- attention (mem rows direct from mk/mv)
#define QR 16
__global__ __launch_bounds__(256) void attn_k(
    const float* __restrict__ q, const float* __restrict__ kbuf,
    const float* __restrict__ vbuf, const float* __restrict__ mk,
    const float* __restrict__ mv, const int* __restrict__ seq_len,
    float* __restrict__ attno)
{
    __shared__ float kv[64 * 68];     // score: [d][key]; PV: [key][d]
    __shared__ float qs[QR][68];
    __shared__ float sc[QR][584];     // 576 + 8 pad
    int b = blockIdx.z, h = blockIdx.y, t0 = blockIdx.x * QR;
    int tid = threadIdx.x, w = tid >> 6, lane = tid & 63;
    int r0 = w * 4;
#pragma unroll
    for (int i = 0; i < 4; i++) {
        int idx = tid + 256 * i;
        int r = idx >> 6, d = idx & 63;
        qs[r][d] = q[((size_t)(b * T_) + t0 + r) * D_ + h * DH_ + d] * 0.125f;
    }
    int sl = seq_len[b];
    int ntv = (sl + 63) >> 6;         // valid T-tiles; memory tile always valid
    int kg = lane & 15, quad = lane >> 4;
    int myrow = r0 + quad;

    // ---- score phase over valid tiles
    for (int ti = 0; ti <= ntv; ti++) {
        int t = (ti < ntv) ? ti : 8;
        int s0 = t * 64;
        __syncthreads();
        {   // stage K as [d][key] (rows from kbuf or memory keys)
            const float* kp = (t < 8)
                ? kbuf + ((size_t)(b * T_) + s0 + w * 16) * D_ + h * DH_ + lane
                : mk + (size_t)(w * 16) * D_ + h * DH_ + lane;
#pragma unroll
            for (int jj = 0; jj < 4; jj++) {
                float4 kf;
                kf.x = kp[(jj * 4 + 0) * D_];
                kf.y = kp[(jj * 4 + 1) * D_];
                kf.z = kp[(jj * 4 + 2) * D_];
                kf.w = kp[(jj * 4 + 3) * D_];
                *(float4*)&kv[lane * 68 + w * 16 + jj * 4] = kf;
            }
        }
        __syncthreads();
        float a0 = 0, a1 = 0, a2 = 0, a3 = 0;
#pragma unroll 8
        for (int d = 0; d < 64; d++) {
            float4 kf = *(const float4*)&kv[d * 68 + kg * 4];
            float qv = qs[myrow][d];
            a0 = fmaf(qv, kf.x, a0);
            a1 = fmaf(qv, kf.y, a1);
            a2 = fmaf(qv, kf.z, a2);
            a3 = fmaf(qv, kf.w, a3);
        }
        int sb = s0 + kg * 4;
        float4 o;
        o.x = (sb + 0 >= T_ || sb + 0 < sl) ? a0 : -1e9f;
        o.y = (sb + 1 >= T_ || sb + 1 < sl) ? a1 : -1e9f;
        o.z = (sb + 2 >= T_ || sb + 2 < sl) ? a2 : -1e9f;
        o.w = (sb + 3 >= T_ || sb + 3 < sl) ? a3 : -1e9f;
        *(float4*)&sc[myrow][s0 + kg * 4] = o;
    }
    __syncthreads();

    // ---- softmax (wave-private rows, valid tiles only)
    float inv[4];
#pragma unroll
    for (int r = 0; r < 4; r++) {
        float mx = -1e30f;
        for (int ti = 0; ti <= ntv; ti++) {
            int s0 = ((ti < ntv) ? ti : 8) * 64;
            mx = fmaxf(mx, sc[r0 + r][s0 + lane]);
        }
        for (int off = 32; off; off >>= 1) mx = fmaxf(mx, __shfl_xor(mx, off));
        float sum = 0.f;
        for (int ti = 0; ti <= ntv; ti++) {
            int s0 = ((ti < ntv) ? ti : 8) * 64;
            float e2 = expf(sc[r0 + r][s0 + lane] - mx);
            sc[r0 + r][s0 + lane] = e2; sum += e2;
        }
        for (int off = 32; off; off >>= 1) sum += __shfl_xor(sum, off);
        inv[r] = 1.f / sum;
    }

    // ---- PV phase (lane = d)
    float o0 = 0, o1 = 0, o2 = 0, o3 = 0;
    for (int ti = 0; ti <= ntv; ti++) {
        int t = (ti < ntv) ? ti : 8;
        int s0 = t * 64;
        __syncthreads();
#pragma unroll
        for (int i = 0; i < 16; i++) {
            int idx = tid + 256 * i;
            int key = idx >> 6, d = idx & 63;
            const float* vp = (t < 8)
                ? vbuf + ((size_t)(b * T_) + s0 + key) * D_ + h * DH_ + d
                : mv + (size_t)key * D_ + h * DH_ + d;
            kv[key * 68 + d] = *vp;
        }
        __syncthreads();
#pragma unroll 4
        for (int g = 0; g < 16; g++) {
            float4 p0 = *(const float4*)&sc[r0 + 0][s0 + g * 4];
            float4 p1 = *(const float4*)&sc[r0 + 1][s0 + g * 4];
            float4 p2 = *(const float4*)&sc[r0 + 2][s0 + g * 4];
            float4 p3 = *(const float4*)&sc[r0 + 3][s0 + g * 4];
            float v0 = kv[(g * 4 + 0) * 68 + lane];
            float v1 = kv[(g * 4 + 1) * 68 + lane];
            float v2 = kv[(g * 4 + 2) * 68 + lane];
            float v3 = kv[(g * 4 + 3) * 68 + lane];
            o0 += p0.x * v0 + p0.y * v1 + p0.z * v2 + p0.w * v3;
            o1 += p1.x * v0 + p1.y * v1 + p1.z * v2 + p1.w * v3;
            o2 += p2.x * v0 + p2.y * v1 + p2.z * v2 + p2.w * v3;
            o3 += p3.x * v0 + p3.y * v1 + p3.z * v2 + p3.w * v3;
        }
    }
    size_t base = ((size_t)(b * T_) + t0 + r0) * D_ + h * DH_ + lane;
    attno[base + 0 * D_] = o0 * inv[0];
    attno[base + 1 * D_] = o1 * inv[1];
    attno[base + 2 * D_] = o2 * inv[2];
    attno[base + 3 * D_] = o3 * inv[3];
}

__global__ void ln_k(const float* __restrict__ o, const float* __restrict__ g,
                     const float* __restrict__ bb, float* __restrict__ cur)
{
    int w = threadIdx.x >> 6, lane = threadIdx.x & 63;
    size_t row = (size_t)(blockIdx.x * 4 + w);
    float v[8]; float s = 0.f;
#pragma unroll
    for (int i = 0; i < 8; i++) {
        int d = lane + 64 * i;
        v[i] = cur[row * D_ + d] + o[row * D_ + d];
        s += v[i];
    }
    for (int off = 32; off; off >>= 1) s += __shfl_xor(s, off);
    float mu = s * (1.f / D_);
    float vs = 0.f;
#pragma unroll
    for (int i = 0; i < 8; i++) { float dd = v[i] - mu; vs += dd * dd; }
    for (int off = 32; off; off >>= 1) vs += __shfl_xor(vs, off);
    float rstd = rsqrtf(vs * (1.f / D_) + 1e-5f);
#pragma unroll
    for (int i = 0; i < 8; i++) {
        int d = lane + 64 * i;
        cur[row * D_ + d] = (v[i] - mu) * rstd * g[d] + bb[d];
    }
}

// reduce impPart[RBLK_][32] -> imp[8][4], then cv^2 sum (deterministic)
__global__ __launch_bounds__(256) void aux_k(const float* __restrict__ impPart,
                                             float* __restrict__ outp)
{
    __shared__ float red[8][32];
    __shared__ float imp[32];
    int tid = threadIdx.x;
    int c = tid & 31, p = tid >> 5;
    float s = 0.f;
    for (int b = p; b < RBLK_; b += 8) s += impPart[(size_t)b * 32 + c];
    red[p][c] = s;
    __syncthreads();
    if (tid < 32) {
        float t = 0.f;
#pragma unroll
        for (int i = 0; i < 8; i++) t += red[i][tid];
        imp[tid] = t;
    }
    __syncthreads();
    if (tid == 0) {
        float total = 0.f;
        for (int l = 0; l < 8; l++) {
            const float* ip = imp + l * 4;
            float m = (ip[0] + ip[1] + ip[2] + ip[3]) * 0.25f;
            float var = 0.f;
            for (int e = 0; e < 4; e++) { float d = ip[e] - m; var += d * d; }
            var *= 0.25f;
            total += var / (m * m + 1e-9f);
        }
        *outp = total;
    }
}

// ============================================================================
extern "C" void kernel_launch(void* const* d_in, const int* in_sizes, int n_in,
                              void* d_out, int out_size, void* d_ws, size_t ws_size,
                              hipStream_t stream)
{
    (void)in_sizes; (void)n_in; (void)out_size; (void)ws_size;
    const float* x        = (const float*)d_in[0];
    const int*   seqlen   = (const int*)d_in[1];
    const float* emb_w1   = (const float*)d_in[2];
    const float* emb_b1   = (const float*)d_in[3];
    const float* emb_w2   = (const float*)d_in[4];
    const float* emb_wo   = (const float*)d_in[5];
    const float* f0_w1    = (const float*)d_in[6];
    const float* f0_b1    = (const float*)d_in[7];
    const float* f0_w2    = (const float*)d_in[8];
    const float* f0_router= (const float*)d_in[9];
    const float* f0_fb    = (const float*)d_in[10];
    const float* f0_fa    = (const float*)d_in[11];
    const float* f_w1     = (const float*)d_in[12];
    const float* f_b1     = (const float*)d_in[13];
    const float* f_w2     = (const float*)d_in[14];
    const float* f_router = (const float*)d_in[15];
    const float* f_fb     = (const float*)d_in[16];
    const float* f_fa     = (const float*)d_in[17];
    const float* attn_wq  = (const float*)d_in[18];
    const float* attn_wk  = (const float*)d_in[19];
    const float* attn_wv  = (const float*)d_in[20];
    const float* attn_wo  = (const float*)d_in[21];
    const float* attn_mk  = (const float*)d_in[22];
    const float* attn_mv  = (const float*)d_in[23];
    const float* ln_g     = (const float*)d_in[24];
    const float* ln_b     = (const float*)d_in[25];
    const float* out_w    = (const float*)d_in[26];
    const float* out_b    = (const float*)d_in[27];

    float* out0 = (float*)d_out;
    float* out1 = out0 + (size_t)BT_ * OUT_;
    float* out2 = out1 + (size_t)BT_ * OUT_;

    float* fws = (float*)d_ws;
    size_t o = 0;
    float* embedF = fws + o; o += (size_t)BT_ * D_;       // 1M floats
    float* curB   = fws + o; o += (size_t)BT_ * D_;       // 1M
    float* hbuf   = fws + o; o += (size_t)BT_ * HID_;     // 2M (h | Ag+hbufh | attno+tmpo)
    float* pbuf   = fws + o; o += (size_t)BT_ * D_;       // 1M (also qbuf)
    float* kbuf   = fws + o; o += (size_t)BT_ * D_;       // 1M (also w1h/woe_h/outw_h)
    float* vbuf   = fws + o; o += (size_t)BT_ * D_;       // 1M (also w2h/w2e_h)
    float* gatev  = fws + o; o += (size_t)8 * BT_;
    float* impPart= fws + o; o += (size_t)RBLK_ * 32;
    float* R2     = fws + o; o += (size_t)8 * 1024 * 4;
    int* eid     = (int*)(fws + o); o += (size_t)8 * BT_;
    int* sortedA = (int*)(fws + o); o += (size_t)8 * BT_;
    int* segA    = (int*)(fws + o); o += 64;
    // ---- aliases (lifetimes disjoint; footprint = proven r8/r9 size)
    __bf16* Ag    = (__bf16*)hbuf;                          // [2048][<=512] bf16
    __bf16* hbufh = (__bf16*)(hbuf + (size_t)BT_ * D_ / 2); // [2048][1024] bf16
    __bf16* w1h   = (__bf16*)kbuf;                          // [4][Kpad][1024] bf16
    __bf16* w2h   = (__bf16*)vbuf;                          // [4][1024][512] bf16
    __bf16* w2e_h = (__bf16*)vbuf;                          // emb_w2 bf16 (pre-loop)
    __bf16* woe_h = (__bf16*)kbuf;                          // emb_wo bf16 (pre-loop)
    __bf16* outw_h= (__bf16*)kbuf;                          // out_w bf16 (post-loop)
    float* qbuf  = pbuf;
    float* attno = hbuf;                                    // attn phase only
    float* tmpo  = hbuf + (size_t)BT_ * D_;

    // h = relu(x@emb_w1+b1) — exact f32 (feeds routing)
    gemm80_k<<<dim3(HID_ / 64, BT_ / 64, 1), 256, 0, stream>>>(x, emb_w1, emb_b1, hbuf);
    wr2_k<<<256, 256, 0, stream>>>(emb_w2, f0_router, f_router, R2);
    routerall_k<<<RBLK_, 256, 0, stream>>>(hbuf, R2, seqlen, eid, gatev, impPart);
    bucketall_k<<<8, 256, 0, stream>>>(eid, sortedA, segA);
    // embed head: pre-convert B (N=4096 f32 B would thrash XCD L2), then GEMM
    cvtw_k<<<256, 256, 0, stream>>>(emb_w2, w2e_h, 9, 10, HID_);
    cvtw_k<<<1024, 256, 0, stream>>>(emb_wo, woe_h, 12, 9, D_);
    dgemm_k<false,true><<<dim3(D_ / 64, BT_ / 128, 1), 256, 0, stream>>>(
        hbuf, w2e_h, nullptr, embedF, D_, HID_);
    dgemm_k<false,true><<<dim3(OUT_ / 64, BT_ / 128, 1), 256, 0, stream>>>(
        embedF, woe_h, nullptr, out1, OUT_, D_);
    // hbuf (h) dead from here.

    for (int l = 0; l < 8; l++) {
        const float* w1  = (l == 0) ? f0_w1 : f_w1 + (size_t)(l-1) * E_ * D_ * HID_;
        const float* b1p = (l == 0) ? f0_b1 : f_b1 + (size_t)(l-1) * E_ * HID_;
        const float* w2  = (l == 0) ? f0_w2 : f_w2 + (size_t)(l-1) * E_ * HID_ * D_;
        const float* fbp = (l == 0) ? f0_fb : f_fb + (size_t)(l-1) * 4 * D_;
        const float* fap = (l == 0) ? f0_fa : f_fa + (size_t)(l-1) * 1 * D_;
        const float* Ain = (l == 0) ? x : curB;
        int lda  = (l == 0) ? IN_ : D_;
        int Ks   = (l == 0) ? IN_ : D_;
        int Kp   = (l == 0) ? 128 : 512;
        int kpsh = (l == 0) ? 7 : 9;
        const int* seg = segA + l * 8;
        const int* sorted = sortedA + l * BT_;

        // fused prep: w1 cvt | w2 cvt | A gather — one launch, 16x reuse kept
        int nb1 = E_ * Kp * HID_ / 8 / 256;
        int nb2 = E_ * HID_ * D_ / 8 / 256;
        int nb3 = BT_ * Kp / 8 / 256;
        prep_k<<<nb1 + nb2 + nb3, 256, 0, stream>>>(
            w1, w2, Ain, lda, sorted, w1h, w2h, Ag, kpsh, Ks, nb1, nb2);

        egemm_k<true><<<dim3(HID_/64, BT_/128, E_), 256, 0, stream>>>(
            Ag, w1h, b1p, hbufh, nullptr, HID_, Kp, seg, nullptr, nullptr);
        egemm_k<false><<<dim3(D_/64, BT_/128, E_), 256, 0, stream>>>(
            hbufh, w2h, nullptr, nullptr, pbuf, D_, HID_, seg, sorted,
            gatev + l * BT_);
        fsmn_k<<<BT_*D_/256, 256, 0, stream>>>(pbuf, fbp, fap, curB,
                                               (l > 0) ? 1 : 0, (l == 3) ? 1 : 0);

        if (l == 3 || l == 7) {
            int ab = (l == 3) ? 0 : 1;
            const float* wq = attn_wq + (size_t)ab * D_ * D_;
            const float* wk = attn_wk + (size_t)ab * D_ * D_;
            const float* wv = attn_wv + (size_t)ab * D_ * D_;
            const float* wo = attn_wo + (size_t)ab * D_ * D_;
            const float* mk = attn_mk + (size_t)ab * M_ * D_;
            const float* mv = attn_mv + (size_t)ab * M_ * D_;
            const float* g  = ln_g + (size_t)ab * D_;
            const float* bb = ln_b + (size_t)ab * D_;

            // kbuf/vbuf (w1h/w2h) dead now; qkv overwrites them with K/V.
            qkv_k<<<dim3(3 * D_ / MBN, BT_ / MBM, 1), 256, 0, stream>>>(
                curB, wq, wk, wv, qbuf, kbuf, vbuf);
            attn_k<<<dim3(T_/QR, H_, B_), 256, 0, stream>>>(
                qbuf, kbuf, vbuf, mk, mv, seqlen, attno);
            // wo is 1MB f32 -> L2-resident; f32-B GEMM, no convert launch
            dgemm_k<false,false><<<dim3(D_ / 64, BT_ / 128, 1), 256, 0, stream>>>(
                attno, wo, nullptr, tmpo, D_, D_);
            ln_k<<<BT_/4, 256, 0, stream>>>(tmpo, g, bb, curB);
        }
    }

    cvtw_k<<<1024, 256, 0, stream>>>(out_w, outw_h, 12, 9, D_);
    dgemm_k<true,true><<<dim3(OUT_ / 64, BT_ / 128, 1), 256, 0, stream>>>(
        curB, outw_h, out_b, out0, OUT_, D_);
    aux_k<<<1, 256, 0, stream>>>(impPart, out2);
}

// Round 8
// 1308.788 us; speedup vs baseline: 1.8596x; 1.0574x over previous
//
#include <hip/hip_runtime.h>
#include <hip/hip_bf16.h>

// ============================================================================
// Net_72662256713812 — round 11: occupancy round.
//  - attn_k: flash-style fused score+online-softmax+PV per tile. Deletes the
//    37.4KB sc buffer -> LDS 59.4->25.6KB -> 4 blocks/CU resident (was 2).
//    Same tile-skip + masking; rescale is f32 reassociation only.
//  - egemm: BM 128->64 (wave tile 32x32, acc 2x2). Active blocks x2
//    (w1 256->512, w2 136->264), LDS 49->32KB -> 2+ blocks/CU so barrier
//    drains of one block hide under the other's compute.
//  - everything else identical to round 10 (1384us baseline).
// ============================================================================

typedef __bf16 bf16x8 __attribute__((ext_vector_type(8)));
typedef float f32x4 __attribute__((ext_vector_type(4)));

#define B_ 4
#define T_ 512
#define IN_ 80
#define OUT_ 4096
#define D_ 512
#define HID_ 1024
#define E_ 4
#define H_ 8
#define DH_ 64
#define M_ 64
#define BT_ (B_ * T_)        // 2048
#define TKV_ (T_ + M_)       // 576
#define RBLK_ (BT_ / 4)      // 512 router blocks

__device__ __forceinline__ unsigned pk2(float a, float b) {
    unsigned short ua = __builtin_bit_cast(unsigned short, (__bf16)a);
    unsigned short ub = __builtin_bit_cast(unsigned short, (__bf16)b);
    return (unsigned)ua | ((unsigned)ub << 16);
}
__device__ __forceinline__ unsigned pkh2(__bf16 a, __bf16 b) {
    unsigned short ua = __builtin_bit_cast(unsigned short, a);
    unsigned short ub = __builtin_bit_cast(unsigned short, b);
    return (unsigned)ua | ((unsigned)ub << 16);
}

// ---------------------------------------------------------------- embed w1 (f32, K=80)
__global__ __launch_bounds__(256) void gemm80_k(
    const float* __restrict__ A,    // [BT_][80]
    const float* __restrict__ Bw,   // [80][1024]
    const float* __restrict__ bias, // [1024]
    float* __restrict__ C)          // [BT_][1024]
{
    __shared__ float As[80][68];   // [k][m]
    __shared__ float Bs[80][68];   // [k][n]
    int m0 = blockIdx.y * 64, n0 = blockIdx.x * 64;
    int tid = threadIdx.x;
#pragma unroll
    for (int i = 0; i < 5; i++) {
        int idx = tid + 256 * i;          // 0..1279
        int m = idx / 20, c = idx % 20;
        float4 f = *(const float4*)&A[(size_t)(m0 + m) * 80 + c * 4];
        As[c * 4 + 0][m] = f.x; As[c * 4 + 1][m] = f.y;
        As[c * 4 + 2][m] = f.z; As[c * 4 + 3][m] = f.w;
    }
#pragma unroll
    for (int i = 0; i < 5; i++) {
        int idx = tid + 256 * i;
        int k = idx / 16, c = idx % 16;
        float4 f = *(const float4*)&Bw[(size_t)k * 1024 + n0 + c * 4];
        *(float4*)&Bs[k][c * 4] = f;
    }
    __syncthreads();
    int tx = tid & 15, ty = tid >> 4;
    float acc[4][4];
#pragma unroll
    for (int j = 0; j < 4; j++)
#pragma unroll
        for (int i = 0; i < 4; i++) acc[j][i] = 0.f;
#pragma unroll 8
    for (int k = 0; k < 80; k++) {
        float4 a = *(const float4*)&As[k][ty * 4];
        float4 b = *(const float4*)&Bs[k][tx * 4];
        float av[4] = {a.x, a.y, a.z, a.w};
        float bv[4] = {b.x, b.y, b.z, b.w};
#pragma unroll
        for (int j = 0; j < 4; j++)
#pragma unroll
            for (int i = 0; i < 4; i++) acc[j][i] += av[j] * bv[i];
    }
#pragma unroll
    for (int j = 0; j < 4; j++) {
        size_t row = (size_t)(m0 + ty * 4 + j);
        float4 o;
        o.x = fmaxf(acc[j][0] + bias[n0 + tx * 4 + 0], 0.f);
        o.y = fmaxf(acc[j][1] + bias[n0 + tx * 4 + 1], 0.f);
        o.z = fmaxf(acc[j][2] + bias[n0 + tx * 4 + 2], 0.f);
        o.w = fmaxf(acc[j][3] + bias[n0 + tx * 4 + 3], 0.f);
        *(float4*)&C[row * 1024 + n0 + tx * 4] = o;
    }
}

// ---------------------------------------------------------------- R2 = emb_w2 @ router_l (f64 accum)
__global__ void wr2_k(const float* __restrict__ w2,   // [1024][512]
                      const float* __restrict__ r0,   // [512][4]
                      const float* __restrict__ rl,   // [7][512][4]
                      float* __restrict__ R2)         // [8][1024][4]
{
    int wv = threadIdx.x >> 6, lane = threadIdx.x & 63;
    int h = blockIdx.x * 4 + wv;
    const float* wrow = w2 + (size_t)h * 512;
    float w[8];
#pragma unroll
    for (int i = 0; i < 8; i++) w[i] = wrow[lane + 64 * i];
    for (int l = 0; l < 8; l++) {
        const float* rp = (l == 0) ? r0 : rl + (size_t)(l - 1) * 2048;
        double a0 = 0, a1 = 0, a2 = 0, a3 = 0;
#pragma unroll
        for (int i = 0; i < 8; i++) {
            int d = lane + 64 * i;
            float4 r = *(const float4*)&rp[d * 4];
            a0 += (double)w[i] * (double)r.x;
            a1 += (double)w[i] * (double)r.y;
            a2 += (double)w[i] * (double)r.z;
            a3 += (double)w[i] * (double)r.w;
        }
        for (int off = 32; off; off >>= 1) {
            a0 += __shfl_xor(a0, off); a1 += __shfl_xor(a1, off);
            a2 += __shfl_xor(a2, off); a3 += __shfl_xor(a3, off);
        }
        if (lane == 0) {
            float4 o = make_float4((float)a0, (float)a1, (float)a2, (float)a3);
            *(float4*)&R2[((size_t)l * 1024 + h) * 4] = o;
        }
    }
}

// ---------------------------------------------------------------- all-layers routing from h
__global__ __launch_bounds__(256) void routerall_k(
    const float* __restrict__ h,    // [BT_][1024]
    const float* __restrict__ R2,   // [8][1024][4]
    const int* __restrict__ seq_len,
    int* __restrict__ eid,          // [8][BT_]
    float* __restrict__ gatev,      // [8][BT_]
    float* __restrict__ impPart)    // [RBLK_][32]
{
    __shared__ float impLoc[4][32];
    int wv = threadIdx.x >> 6, lane = threadIdx.x & 63;
    int tok = blockIdx.x * 4 + wv;
    const float* hr = h + (size_t)tok * 1024;
    float acc[8][4];
#pragma unroll
    for (int l = 0; l < 8; l++)
#pragma unroll
        for (int e = 0; e < 4; e++) acc[l][e] = 0.f;
    for (int i = 0; i < 16; i++) {
        int d = lane + 64 * i;
        float hv = hr[d];
#pragma unroll
        for (int l = 0; l < 8; l++) {
            float4 r = *(const float4*)&R2[((size_t)l * 1024 + d) * 4];
            acc[l][0] += hv * r.x; acc[l][1] += hv * r.y;
            acc[l][2] += hv * r.z; acc[l][3] += hv * r.w;
        }
    }
    for (int off = 32; off; off >>= 1) {
#pragma unroll
        for (int l = 0; l < 8; l++)
#pragma unroll
            for (int e = 0; e < 4; e++) acc[l][e] += __shfl_xor(acc[l][e], off);
    }
    if (lane == 0) {
        int b = tok >> 9, t = tok & 511;
        bool valid = t < seq_len[b];
        for (int l = 0; l < 8; l++) {
            float lg[4] = {acc[l][0], acc[l][1], acc[l][2], acc[l][3]};
            float mx = fmaxf(fmaxf(lg[0], lg[1]), fmaxf(lg[2], lg[3]));
            float g[4], s = 0.f;
            for (int e = 0; e < 4; e++) { g[e] = expf(lg[e] - mx); s += g[e]; }
            float inv = 1.f / s;
            int am = 0; float bv = g[0];
            for (int e = 1; e < 4; e++) if (g[e] > bv) { bv = g[e]; am = e; }
            eid[l * BT_ + tok] = am;
            gatev[l * BT_ + tok] = bv * inv;
            for (int e = 0; e < 4; e++)
                impLoc[wv][l * 4 + e] = valid ? g[e] * inv : 0.f;
        }
    }
    __syncthreads();
    int tid = threadIdx.x;
    if (tid < 32) {
        float s = impLoc[0][tid] + impLoc[1][tid] + impLoc[2][tid] + impLoc[3][tid];
        impPart[(size_t)blockIdx.x * 32 + tid] = s;
    }
}

// ---------------------------------------------------------------- convert / gather bodies
__device__ __forceinline__ void cvt_body(const float* __restrict__ src,
                                         __bf16* __restrict__ dst,
                                         int idx, int nsh, int kpsh, int Ksrc)
{
    int cprsh = nsh - 3;
    int row = idx >> cprsh;                      // e*Kpad + k
    int chunk = idx & ((1 << cprsh) - 1);
    int e = row >> kpsh, k = row & ((1 << kpsh) - 1);
    int n = chunk * 8;
    uint4 pk;
    if (k < Ksrc) {
        const float* sp = src + (((size_t)e * Ksrc + k) << nsh) + n;
        float4 f0 = *(const float4*)sp;
        float4 f1 = *(const float4*)(sp + 4);
        pk = make_uint4(pk2(f0.x, f0.y), pk2(f0.z, f0.w),
                        pk2(f1.x, f1.y), pk2(f1.z, f1.w));
    } else pk = make_uint4(0, 0, 0, 0);
    *(uint4*)&dst[(((size_t)row) << nsh) + n] = pk;
}

__device__ __forceinline__ void gather_body(const float* __restrict__ src, int lda,
                                            const int* __restrict__ sorted,
                                            __bf16* __restrict__ dst,
                                            int idx, int kpsh, int Ksrc)
{
    int cprsh = kpsh - 3;
    int row = idx >> cprsh;
    int chunk = idx & ((1 << cprsh) - 1);
    int k0 = chunk * 8;
    uint4 pk;
    if (k0 < Ksrc) {
        const float* sp = src + (size_t)sorted[row] * lda + k0;
        float4 f0 = *(const float4*)sp;
        float4 f1 = *(const float4*)(sp + 4);
        pk = make_uint4(pk2(f0.x, f0.y), pk2(f0.z, f0.w),
                        pk2(f1.x, f1.y), pk2(f1.z, f1.w));
    } else pk = make_uint4(0, 0, 0, 0);
    *(uint4*)&dst[((size_t)row << kpsh) + k0] = pk;
}

// standalone convert (pre/post-loop weights)
__global__ void cvtw_k(const float* __restrict__ src, __bf16* __restrict__ dst,
                       int nsh, int kpsh, int Ksrc)
{
    cvt_body(src, dst, blockIdx.x * 256 + threadIdx.x, nsh, kpsh, Ksrc);
}

// fused per-layer prep: w1 cvt | w2 cvt | A gather (one launch)
__global__ void prep_k(const float* __restrict__ w1, const float* __restrict__ w2,
                       const float* __restrict__ Ain, int lda,
                       const int* __restrict__ sorted,
                       __bf16* __restrict__ w1h, __bf16* __restrict__ w2h,
                       __bf16* __restrict__ Ag,
                       int kpsh, int Ks, int nb1, int nb2)
{
    int bx = blockIdx.x;
    if (bx < nb1) {
        cvt_body(w1, w1h, bx * 256 + threadIdx.x, 10, kpsh, Ks);
    } else if (bx < nb1 + nb2) {
        cvt_body(w2, w2h, (bx - nb1) * 256 + threadIdx.x, 9, 10, HID_);
    } else {
        gather_body(Ain, lda, sorted, Ag, (bx - nb1 - nb2) * 256 + threadIdx.x,
                    kpsh, Ks);
    }
}

// ---------------------------------------------------------------- pipelined expert GEMM (bf16 in; BM=64)
template<bool W1OUT>
__global__ __launch_bounds__(256) void egemm_k(
    const __bf16* __restrict__ Ag, const __bf16* __restrict__ Bh,
    const float* __restrict__ bias,
    __bf16* __restrict__ Cb, float* __restrict__ Cf,
    int N, int Kpad,
    const int* __restrict__ seg, const int* __restrict__ sorted,
    const float* __restrict__ scale)
{
    __shared__ __align__(16) __bf16 As[2][64 * 64];
    __shared__ __align__(16) __bf16 Bs[2][64 * 64];

    int e = blockIdx.z;
    int row0 = seg[e], cnt = seg[e + 1] - row0;
    int m0 = blockIdx.y * 64;
    if (m0 >= cnt) return;
    int n0 = blockIdx.x * 64;
    const __bf16* Bp = Bh + (size_t)e * Kpad * N;

    int tid = threadIdx.x;
    // A staging: 4 threads/row, 2 chunks of 8 bf16 each
    int arow = tid >> 2, aq = tid & 3;
    int mclamp = min(m0 + arow, cnt - 1);
    const __bf16* aptr = Ag + (size_t)(row0 + mclamp) * Kpad + aq * 16;
    int asb = arow * 64;
    int ac0 = aq * 2;
    int arx = arow & 7;
    // B staging: 64 cols x 64 k, transposed scalar loads
    int bn = tid & 63, bkc = tid >> 6;
    const __bf16* bptr = Bp + n0 + bn;
    int bsb = bn * 64;
    int brx = bn & 7;

    int lane = tid & 63, wid = tid >> 6;
    int wm = wid & 1, wn = wid >> 1;
    int l15 = lane & 15, quad = lane >> 4;

    int aoff[2][2], boff[2][2];
#pragma unroll
    for (int mt = 0; mt < 2; mt++) {
        int m = wm * 32 + mt * 16 + l15;
#pragma unroll
        for (int s = 0; s < 2; s++)
            aoff[mt][s] = m * 64 + (((s * 4 + quad) ^ (m & 7)) * 8);
    }
#pragma unroll
    for (int nt = 0; nt < 2; nt++) {
        int n = wn * 32 + nt * 16 + l15;
#pragma unroll
        for (int s = 0; s < 2; s++)
            boff[nt][s] = n * 64 + (((s * 4 + quad) ^ (n & 7)) * 8);
    }

    f32x4 acc[2][2];
#pragma unroll
    for (int mt = 0; mt < 2; mt++)
#pragma unroll
        for (int nt = 0; nt < 2; nt++)
#pragma unroll
            for (int r = 0; r < 4; r++) acc[mt][nt][r] = 0.f;

    uint4 rA[2]; unsigned rB[8];
    auto stage = [&](int k0) {
#pragma unroll
        for (int j = 0; j < 2; j++) rA[j] = *(const uint4*)(aptr + k0 + j * 8);
#pragma unroll
        for (int c = 0; c < 2; c++) {
            int kk = k0 + (bkc * 2 + c) * 8;
#pragma unroll
            for (int i = 0; i < 4; i++)
                rB[c * 4 + i] = pkh2(bptr[(size_t)(kk + 2 * i) * N],
                                     bptr[(size_t)(kk + 2 * i + 1) * N]);
        }
    };
    auto commit = [&](int buf) {
#pragma unroll
        for (int j = 0; j < 2; j++)
            *(uint4*)&As[buf][asb + (((ac0 + j) ^ arx) * 8)] = rA[j];
#pragma unroll
        for (int c = 0; c < 2; c++)
            *(uint4*)&Bs[buf][bsb + (((bkc * 2 + c) ^ brx) * 8)] =
                make_uint4(rB[c * 4 + 0], rB[c * 4 + 1], rB[c * 4 + 2], rB[c * 4 + 3]);
    };

    stage(0); commit(0); __syncthreads();
    int nt_ = Kpad >> 6;
    for (int t = 0; t < nt_; t++) {
        int buf = t & 1;
        if (t + 1 < nt_) stage((t + 1) << 6);
        bf16x8 af[2][2], bfr[2][2];
#pragma unroll
        for (int mt = 0; mt < 2; mt++)
#pragma unroll
            for (int s = 0; s < 2; s++)
                af[mt][s] = *(const bf16x8*)&As[buf][aoff[mt][s]];
#pragma unroll
        for (int ntx = 0; ntx < 2; ntx++)
#pragma unroll
            for (int s = 0; s < 2; s++)
                bfr[ntx][s] = *(const bf16x8*)&Bs[buf][boff[ntx][s]];
#pragma unroll
        for (int mt = 0; mt < 2; mt++)
#pragma unroll
            for (int ntx = 0; ntx < 2; ntx++)
#pragma unroll
                for (int s = 0; s < 2; s++)
                    acc[mt][ntx] = __builtin_amdgcn_mfma_f32_16x16x32_bf16(
                        af[mt][s], bfr[ntx][s], acc[mt][ntx], 0, 0, 0);
        if (t + 1 < nt_) commit(buf ^ 1);
        __syncthreads();
    }

#pragma unroll
    for (int mt = 0; mt < 2; mt++) {
#pragma unroll
        for (int r = 0; r < 4; r++) {
            int m = m0 + wm * 32 + mt * 16 + quad * 4 + r;
            if (m >= cnt) continue;
            if (W1OUT) {
                size_t ci = (size_t)(row0 + m);
#pragma unroll
                for (int ntx = 0; ntx < 2; ntx++) {
                    int col = n0 + wn * 32 + ntx * 16 + l15;
                    float v = acc[mt][ntx][r] + bias[e * N + col];
                    Cb[ci * N + col] = (__bf16)fmaxf(v, 0.f);
                }
            } else {
                int tok = sorted[row0 + m];
                float sc = scale[tok];
#pragma unroll
                for (int ntx = 0; ntx < 2; ntx++) {
                    int col = n0 + wn * 32 + ntx * 16 + l15;
                    Cf[(size_t)tok * N + col] = acc[mt][ntx][r] * sc;
                }
            }
        }
    }
}

// ---------------------------------------------------------------- pipelined dense GEMM (A f32; B bf16 or f32)
template<bool BIAS, bool BF16B>
__global__ __launch_bounds__(256) void dgemm_k(
    const float* __restrict__ A,          // [2048][K] f32
    const void* __restrict__ Bv,          // [K][N] bf16 or f32
    const float* __restrict__ bias,
    float* __restrict__ C,                // [2048][N]
    int N, int K)
{
    __shared__ __align__(16) __bf16 As[2][128 * 64];
    __shared__ __align__(16) __bf16 Bs[2][64 * 64];

    int m0 = blockIdx.y * 128, n0 = blockIdx.x * 64;
    int tid = threadIdx.x;
    int arow = tid >> 1, ahalf = tid & 1;
    const float* aptr = A + (size_t)(m0 + arow) * K + ahalf * 32;
    int asb = arow * 64, ac0 = ahalf * 4, arx = arow & 7;
    int bn = tid & 63, bkc = tid >> 6;
    const __bf16* bh = (const __bf16*)Bv;
    const float*  bf = (const float*)Bv;
    int bsb = bn * 64, brx = bn & 7;

    int lane = tid & 63, wid = tid >> 6;
    int wm = wid & 1, wn = wid >> 1;
    int l15 = lane & 15, quad = lane >> 4;

    int aoff[4][2], boff[2][2];
#pragma unroll
    for (int mt = 0; mt < 4; mt++) {
        int m = wm * 64 + mt * 16 + l15;
#pragma unroll
        for (int s = 0; s < 2; s++)
            aoff[mt][s] = m * 64 + (((s * 4 + quad) ^ (m & 7)) * 8);
    }
#pragma unroll
    for (int nt = 0; nt < 2; nt++) {
        int n = wn * 32 + nt * 16 + l15;
#pragma unroll
        for (int s = 0; s < 2; s++)
            boff[nt][s] = n * 64 + (((s * 4 + quad) ^ (n & 7)) * 8);
    }

    f32x4 acc[4][2];
#pragma unroll
    for (int mt = 0; mt < 4; mt++)
#pragma unroll
        for (int nt = 0; nt < 2; nt++)
#pragma unroll
            for (int r = 0; r < 4; r++) acc[mt][nt][r] = 0.f;

    uint4 rA[4]; unsigned rB[8];
    auto stage = [&](int k0) {
#pragma unroll
        for (int j = 0; j < 4; j++) {
            float4 f0 = *(const float4*)(aptr + k0 + j * 8);
            float4 f1 = *(const float4*)(aptr + k0 + j * 8 + 4);
            rA[j] = make_uint4(pk2(f0.x, f0.y), pk2(f0.z, f0.w),
                               pk2(f1.x, f1.y), pk2(f1.z, f1.w));
        }
#pragma unroll
        for (int c = 0; c < 2; c++) {
            int kk = k0 + (bkc * 2 + c) * 8;
#pragma unroll
            for (int i = 0; i < 4; i++) {
                if (BF16B)
                    rB[c * 4 + i] = pkh2(bh[(size_t)(kk + 2 * i) * N + n0 + bn],
                                         bh[(size_t)(kk + 2 * i + 1) * N + n0 + bn]);
                else
                    rB[c * 4 + i] = pk2(bf[(size_t)(kk + 2 * i) * N + n0 + bn],
                                        bf[(size_t)(kk + 2 * i + 1) * N + n0 + bn]);
            }
        }
    };
    auto commit = [&](int buf) {
#pragma unroll
        for (int j = 0; j < 4; j++)
            *(uint4*)&As[buf][asb + (((ac0 + j) ^ arx) * 8)] = rA[j];
#pragma unroll
        for (int c = 0; c < 2; c++)
            *(uint4*)&Bs[buf][bsb + (((bkc * 2 + c) ^ brx) * 8)] =
                make_uint4(rB[c * 4 + 0], rB[c * 4 + 1], rB[c * 4 + 2], rB[c * 4 + 3]);
    };

    stage(0); commit(0); __syncthreads();
    int nt_ = K >> 6;
    for (int t = 0; t < nt_; t++) {
        int buf = t & 1;
        if (t + 1 < nt_) stage((t + 1) << 6);
        bf16x8 af[4][2], bfr[2][2];
#pragma unroll
        for (int mt = 0; mt < 4; mt++)
#pragma unroll
            for (int s = 0; s < 2; s++)
                af[mt][s] = *(const bf16x8*)&As[buf][aoff[mt][s]];
#pragma unroll
        for (int ntx = 0; ntx < 2; ntx++)
#pragma unroll
            for (int s = 0; s < 2; s++)
                bfr[ntx][s] = *(const bf16x8*)&Bs[buf][boff[ntx][s]];
#pragma unroll
        for (int mt = 0; mt < 4; mt++)
#pragma unroll
            for (int ntx = 0; ntx < 2; ntx++)
#pragma unroll
                for (int s = 0; s < 2; s++)
                    acc[mt][ntx] = __builtin_amdgcn_mfma_f32_16x16x32_bf16(
                        af[mt][s], bfr[ntx][s], acc[mt][ntx], 0, 0, 0);
        if (t + 1 < nt_) commit(buf ^ 1);
        __syncthreads();
    }

#pragma unroll
    for (int mt = 0; mt < 4; mt++) {
#pragma unroll
        for (int r = 0; r < 4; r++) {
            int m = m0 + wm * 64 + mt * 16 + quad * 4 + r;
#pragma unroll
            for (int ntx = 0; ntx < 2; ntx++) {
                int col = n0 + wn * 32 + ntx * 16 + l15;
                float v = acc[mt][ntx][r];
                if (BIAS) v += bias[col];
                C[(size_t)m * N + col] = v;
            }
        }
    }
}

// ---------------------------------------------------------------- fused QKV MFMA GEMM (f32 weights)
#define MBM 128
#define MBN 64
#define MBK 32
#define LDAS 40

__global__ __launch_bounds__(256) void qkv_k(
    const float* __restrict__ A,          // [BT_][512]
    const float* __restrict__ wq, const float* __restrict__ wk,
    const float* __restrict__ wv,
    float* __restrict__ qo, float* __restrict__ ko, float* __restrict__ vo)
{
    __shared__ __align__(16) __bf16 As[MBM * LDAS];
    __shared__ __align__(16) __bf16 Bs[MBN * LDAS];

    int n0g = blockIdx.x * MBN;
    int which = n0g >> 9;
    int n0 = n0g & 511;
    const float* Bp = (which == 0) ? wq : (which == 1) ? wk : wv;
    float* Cp = (which == 0) ? qo : (which == 1) ? ko : vo;
    int m0 = blockIdx.y * MBM;

    int tid = threadIdx.x;
    int arow = tid >> 1, ahalf = tid & 1;
    const float* aptr = A + (size_t)(m0 + arow) * D_ + ahalf * 16;
    int asw = (arow >> 3) & 3;
    int bn = tid & 63, bkc = tid >> 6;
    int bcs = bkc ^ ((bn >> 3) & 3);

    int lane = tid & 63, wid = tid >> 6;
    int wm = wid & 1, wn = wid >> 1;
    int l15 = lane & 15, quad = lane >> 4;

    int aoff[4], boff[2];
#pragma unroll
    for (int mt = 0; mt < 4; mt++) {
        int m = wm * 64 + mt * 16 + l15;
        aoff[mt] = m * LDAS + (quad ^ ((m >> 3) & 3)) * 8;
    }
#pragma unroll
    for (int nt = 0; nt < 2; nt++) {
        int n = wn * 32 + nt * 16 + l15;
        boff[nt] = n * LDAS + (quad ^ ((n >> 3) & 3)) * 8;
    }

    f32x4 acc[4][2];
#pragma unroll
    for (int mt = 0; mt < 4; mt++)
#pragma unroll
        for (int nt = 0; nt < 2; nt++)
#pragma unroll
            for (int r = 0; r < 4; r++) acc[mt][nt][r] = 0.f;

    for (int k0 = 0; k0 < D_; k0 += MBK) {
#pragma unroll
        for (int cc = 0; cc < 2; cc++) {
            float4 f0 = *(const float4*)(aptr + k0 + cc * 8);
            float4 f1 = *(const float4*)(aptr + k0 + cc * 8 + 4);
            uint4 pk = make_uint4(pk2(f0.x, f0.y), pk2(f0.z, f0.w),
                                  pk2(f1.x, f1.y), pk2(f1.z, f1.w));
            int cs = (ahalf * 2 + cc) ^ asw;
            *(uint4*)&As[arow * LDAS + cs * 8] = pk;
        }
        {
            float f[8];
            int kk = k0 + bkc * 8;
#pragma unroll
            for (int i = 0; i < 8; i++)
                f[i] = Bp[(size_t)(kk + i) * D_ + n0 + bn];
            uint4 pk = make_uint4(pk2(f[0], f[1]), pk2(f[2], f[3]),
                                  pk2(f[4], f[5]), pk2(f[6], f[7]));
            *(uint4*)&Bs[bn * LDAS + bcs * 8] = pk;
        }
        __syncthreads();
        bf16x8 af[4], bfm[2];
#pragma unroll
        for (int mt = 0; mt < 4; mt++) af[mt] = *(const bf16x8*)&As[aoff[mt]];
#pragma unroll
        for (int nt = 0; nt < 2; nt++) bfm[nt] = *(const bf16x8*)&Bs[boff[nt]];
#pragma unroll
        for (int mt = 0; mt < 4; mt++)
#pragma unroll
            for (int nt = 0; nt < 2; nt++)
                acc[mt][nt] = __builtin_amdgcn_mfma_f32_16x16x32_bf16(
                    af[mt], bfm[nt], acc[mt][nt], 0, 0, 0);
        __syncthreads();
    }

#pragma unroll
    for (int mt = 0; mt < 4; mt++) {
#pragma unroll
        for (int r = 0; r < 4; r++) {
            int mi = wm * 64 + mt * 16 + quad * 4 + r;
            int m = m0 + mi;
#pragma unroll
            for (int nt = 0; nt < 2; nt++) {
                int col = n0 + wn * 32 + nt * 16 + l15;
                Cp[(size_t)m * D_ + col] = acc[mt][nt][r];
            }
        }
    }
}

// ---------------------------------------------------------------- small ops
__global__ void bucketall_k(const int* __restrict__ eidA, int* __restrict__ sortedA,
                            int* __restrict__ segA)
{
    __shared__ int cnt[E_]; __shared__ int cur[E_];
    int l = blockIdx.x;
    const int* eid = eidA + l * BT_;
    int* sorted = sortedA + l * BT_;
    int* seg = segA + l * 8;
    int tid = threadIdx.x;
    if (tid < E_) cnt[tid] = 0;
    __syncthreads();
    for (int t = tid; t < BT_; t += 256) atomicAdd(&cnt[eid[t]], 1);
    __syncthreads();
    if (tid == 0) {
        int o = 0;
        for (int e = 0; e < E_; e++) { seg[e] = o; cur[e] = o; o += cnt[e]; }
        seg[E_] = o;
    }
    __syncthreads();
    for (int t = tid; t < BT_; t += 256) {
        int pos = atomicAdd(&cur[eid[t]], 1);
        sorted[pos] = t;
    }
}

// fsmn + optional skip + optional fused positional encoding
__global__ void fsmn_k(const float* __restrict__ p, const float* __restrict__ fb,
                       const float* __restrict__ fa, float* __restrict__ cur,
                       int skip, int pe)
{
    int idx = blockIdx.x * 256 + threadIdx.x;
    int d = idx & 511;
    int t = (idx >> 9) & 511;
    float m = p[idx];
#pragma unroll
    for (int k = 0; k < 4; k++) {
        int tt = t - 2 * (k + 1);
        if (tt >= 0) m += fb[k * D_ + d] * p[idx - D_ * 2 * (k + 1)];
    }
    if (t + 1 < T_) m += fa[d] * p[idx + D_];
    if (skip) m += cur[idx];
    if (pe) {
        float div = expf((float)(d & ~1) * (-9.210340371976184f / (float)D_));
        float ang = (float)t * div;
        m += (d & 1) ? cosf(ang) : sinf(ang);
    }
    cur[idx] = m;
}

// ---------------------------------------------------------------- attention v3: flash-style fused pass
// per block: (b, h, 16 q rows); per 64-key tile: K stage -> scores (regs) ->
// online softmax update -> V stage -> PV accumulate with rescale.
// LDS 25.6KB (was 59.4) -> 4 blocks/CU resident.
#define QR 16
__global__ __launch_bounds__(256) void attn_k(
    const float* __restrict__ q, const float* __restrict__ kbuf,
    const float* __restrict__ vbuf, const float* __restrict__ mk,
    const float* __restrict__ mv, const int* __restrict__ seq_len,
    float* __restrict__ attno)
{
    __shared__ float kv[64 * 68];     // K: [d][key]; V: [key][d]
    __shared__ float qs[QR][68];
    __shared__ float pt[4][4][68];    // [wave][row][key]
    int b = blockIdx.z, h = blockIdx.y, t0 = blockIdx.x * QR;
    int tid = threadIdx.x, w = tid >> 6, lane = tid & 63;
    int r0 = w * 4;
#pragma unroll
    for (int i = 0; i < 4; i++) {
        int idx = tid + 256 * i;
        int r = idx >> 6, d = idx & 63;
        qs[r][d] = q[((size_t)(b * T_) + t0 + r) * D_ + h * DH_ + d] * 0.125f;
    }
    int sl = seq_len[b];
    int ntv = (sl + 63) >> 6;         // valid T-tiles; memory tile always valid
    int kg = lane & 15, quad = lane >> 4;
    int myrow = r0 + quad;

    float Mrow = -1e30f, Srow = 0.f;  // per-lane: row = myrow (score layout)
    float o0 = 0, o1 = 0, o2 = 0, o3 = 0;   // PV layout: lane = d

    for (int ti = 0; ti <= ntv; ti++) {
        int t = (ti < ntv) ? ti : 8;
        int s0 = t * 64;
        __syncthreads();              // prev PV done (and qs ready on ti=0)
        {   // stage K as [d][key]
            const float* kp = (t < 8)
                ? kbuf + ((size_t)(b * T_) + s0 + w * 16) * D_ + h * DH_ + lane
                : mk + (size_t)(w * 16) * D_ + h * DH_ + lane;
#pragma unroll
            for (int jj = 0; jj < 4; jj++) {
                float4 kf;
                kf.x = kp[(jj * 4 + 0) * D_];
                kf.y = kp[(jj * 4 + 1) * D_];
                kf.z = kp[(jj * 4 + 2) * D_];
                kf.w = kp[(jj * 4 + 3) * D_];
                *(float4*)&kv[lane * 68 + w * 16 + jj * 4] = kf;
            }
        }
        __syncthreads();
        // scores: 4 keys/lane x row/quad
        float a0 = 0, a1 = 0, a2 = 0, a3 = 0;
#pragma unroll 8
        for (int d = 0; d < 64; d++) {
            float4 kf = *(const float4*)&kv[d * 68 + kg * 4];
            float qv = qs[myrow][d];
            a0 = fmaf(qv, kf.x, a0);
            a1 = fmaf(qv, kf.y, a1);
            a2 = fmaf(qv, kf.z, a2);
            a3 = fmaf(qv, kf.w, a3);
        }
        int sb = s0 + kg * 4;
        if (!(sb + 0 >= T_ || sb + 0 < sl)) a0 = -1e9f;
        if (!(sb + 1 >= T_ || sb + 1 < sl)) a1 = -1e9f;
        if (!(sb + 2 >= T_ || sb + 2 < sl)) a2 = -1e9f;
        if (!(sb + 3 >= T_ || sb + 3 < sl)) a3 = -1e9f;
        // online softmax update (16-lane row groups)
        float tmax = fmaxf(fmaxf(a0, a1), fmaxf(a2, a3));
#pragma unroll
        for (int off = 1; off < 16; off <<= 1)
            tmax = fmaxf(tmax, __shfl_xor(tmax, off));
        float Mnew = fmaxf(Mrow, tmax);
        float p0 = expf(a0 - Mnew), p1 = expf(a1 - Mnew);
        float p2 = expf(a2 - Mnew), p3 = expf(a3 - Mnew);
        float f = expf(Mrow - Mnew);
        float ts = p0 + p1 + p2 + p3;
#pragma unroll
        for (int off = 1; off < 16; off <<= 1) ts += __shfl_xor(ts, off);
        Srow = Srow * f + ts;
        Mrow = Mnew;
        *(float4*)&pt[w][quad][kg * 4] = make_float4(p0, p1, p2, p3);
        float fr0 = __shfl(f, 0),  fr1 = __shfl(f, 16);
        float fr2 = __shfl(f, 32), fr3 = __shfl(f, 48);
        __syncthreads();              // all waves done reading K
        {   // stage V as [key][d]
#pragma unroll
            for (int i = 0; i < 16; i++) {
                int idx = tid + 256 * i;
                int key = idx >> 6, d = idx & 63;
                const float* vp = (t < 8)
                    ? vbuf + ((size_t)(b * T_) + s0 + key) * D_ + h * DH_ + d
                    : mv + (size_t)key * D_ + h * DH_ + d;
                kv[key * 68 + d] = *vp;
            }
        }
        __syncthreads();
        // PV accumulate with rescale (lane = d)
        o0 *= fr0; o1 *= fr1; o2 *= fr2; o3 *= fr3;
#pragma unroll 4
        for (int g = 0; g < 16; g++) {
            float4 p0v = *(const float4*)&pt[w][0][g * 4];
            float4 p1v = *(const float4*)&pt[w][1][g * 4];
            float4 p2v = *(const float4*)&pt[w][2][g * 4];
            float4 p3v = *(const float4*)&pt[w][3][g * 4];
            float v0 = kv[(g * 4 + 0) * 68 + lane];
            float v1 = kv[(g * 4 + 1) * 68 + lane];
            float v2 = kv[(g * 4 + 2) * 68 + lane];
            float v3 = kv[(g * 4 + 3) * 68 + lane];
            o0 += p0v.x * v0 + p0v.y * v1 + p0v.z * v2 + p0v.w * v3;
            o1 += p1v.x * v0 + p1v.y * v1 + p1v.z * v2 + p1v.w * v3;
            o2 += p2v.x * v0 + p2v.y * v1 + p2v.z * v2 + p2v.w * v3;
            o3 += p3v.x * v0 + p3v.y * v1 + p3v.z * v2 + p3v.w * v3;
        }
    }
    float i0 = 1.f / __shfl(Srow, 0);
    float i1 = 1.f / __shfl(Srow, 16);
    float i2 = 1.f / __shfl(Srow, 32);
    float i3 = 1.f / __shfl(Srow, 48);
    size_t base = ((size_t)(b * T_) + t0 + r0) * D_ + h * DH_ + lane;
    attno[base + 0 * D_] = o0 * i0;
    attno[base + 1 * D_] = o1 * i1;
    attno[base + 2 * D_] = o2 * i2;
    attno[base + 3 * D_] = o3 * i3;
}

__global__ void ln_k(const float* __restrict__ o, const float* __restrict__ g,
                     const float* __restrict__ bb, float* __restrict__ cur)
{
    int w = threadIdx.x >> 6, lane = threadIdx.x & 63;
    size_t row = (size_t)(blockIdx.x * 4 + w);
    float v[8]; float s = 0.f;
#pragma unroll
    for (int i = 0; i < 8; i++) {
        int d = lane + 64 * i;
        v[i] = cur[row * D_ + d] + o[row * D_ + d];
        s += v[i];
    }
    for (int off = 32; off; off >>= 1) s += __shfl_xor(s, off);
    float mu = s * (1.f / D_);
    float vs = 0.f;
#pragma unroll
    for (int i = 0; i < 8; i++) { float dd = v[i] - mu; vs += dd * dd; }
    for (int off = 32; off; off >>= 1) vs += __shfl_xor(vs, off);
    float rstd = rsqrtf(vs * (1.f / D_) + 1e-5f);
#pragma unroll
    for (int i = 0; i < 8; i++) {
        int d = lane + 64 * i;
        cur[row * D_ + d] = (v[i] - mu) * rstd * g[d] + bb[d];
    }
}

// reduce impPart[RBLK_][32] -> imp[8][4], then cv^2 sum (deterministic)
__global__ __launch_bounds__(256) void aux_k(const float* __restrict__ impPart,
                                             float* __restrict__ outp)
{
    __shared__ float red[8][32];
    __shared__ float imp[32];
    int tid = threadIdx.x;
    int c = tid & 31, p = tid >> 5;
    float s = 0.f;
    for (int b = p; b < RBLK_; b += 8) s += impPart[(size_t)b * 32 + c];
    red[p][c] = s;
    __syncthreads();
    if (tid < 32) {
        float t = 0.f;
#pragma unroll
        for (int i = 0; i < 8; i++) t += red[i][tid];
        imp[tid] = t;
    }
    __syncthreads();
    if (tid == 0) {
        float total = 0.f;
        for (int l = 0; l < 8; l++) {
            const float* ip = imp + l * 4;
            float m = (ip[0] + ip[1] + ip[2] + ip[3]) * 0.25f;
            float var = 0.f;
            for (int e = 0; e < 4; e++) { float d = ip[e] - m; var += d * d; }
            var *= 0.25f;
            total += var / (m * m + 1e-9f);
        }
        *outp = total;
    }
}

// ============================================================================
extern "C" void kernel_launch(void* const* d_in, const int* in_sizes, int n_in,
                              void* d_out, int out_size, void* d_ws, size_t ws_size,
                              hipStream_t stream)
{
    (void)in_sizes; (void)n_in; (void)out_size; (void)ws_size;
    const float* x        = (const float*)d_in[0];
    const int*   seqlen   = (const int*)d_in[1];
    const float* emb_w1   = (const float*)d_in[2];
    const float* emb_b1   = (const float*)d_in[3];
    const float* emb_w2   = (const float*)d_in[4];
    const float* emb_wo   = (const float*)d_in[5];
    const float* f0_w1    = (const float*)d_in[6];
    const float* f0_b1    = (const float*)d_in[7];
    const float* f0_w2    = (const float*)d_in[8];
    const float* f0_router= (const float*)d_in[9];
    const float* f0_fb    = (const float*)d_in[10];
    const float* f0_fa    = (const float*)d_in[11];
    const float* f_w1     = (const float*)d_in[12];
    const float* f_b1     = (const float*)d_in[13];
    const float* f_w2     = (const float*)d_in[14];
    const float* f_router = (const float*)d_in[15];
    const float* f_fb     = (const float*)d_in[16];
    const float* f_fa     = (const float*)d_in[17];
    const float* attn_wq  = (const float*)d_in[18];
    const float* attn_wk  = (const float*)d_in[19];
    const float* attn_wv  = (const float*)d_in[20];
    const float* attn_wo  = (const float*)d_in[21];
    const float* attn_mk  = (const float*)d_in[22];
    const float* attn_mv  = (const float*)d_in[23];
    const float* ln_g     = (const float*)d_in[24];
    const float* ln_b     = (const float*)d_in[25];
    const float* out_w    = (const float*)d_in[26];
    const float* out_b    = (const float*)d_in[27];

    float* out0 = (float*)d_out;
    float* out1 = out0 + (size_t)BT_ * OUT_;
    float* out2 = out1 + (size_t)BT_ * OUT_;

    float* fws = (float*)d_ws;
    size_t o = 0;
    float* embedF = fws + o; o += (size_t)BT_ * D_;       // 1M floats
    float* curB   = fws + o; o += (size_t)BT_ * D_;       // 1M
    float* hbuf   = fws + o; o += (size_t)BT_ * HID_;     // 2M (h | Ag+hbufh | attno+tmpo)
    float* pbuf   = fws + o; o += (size_t)BT_ * D_;       // 1M (also qbuf)
    float* kbuf   = fws + o; o += (size_t)BT_ * D_;       // 1M (also w1h/woe_h/outw_h)
    float* vbuf   = fws + o; o += (size_t)BT_ * D_;       // 1M (also w2h/w2e_h)
    float* gatev  = fws + o; o += (size_t)8 * BT_;
    float* impPart= fws + o; o += (size_t)RBLK_ * 32;
    float* R2     = fws + o; o += (size_t)8 * 1024 * 4;
    int* eid     = (int*)(fws + o); o += (size_t)8 * BT_;
    int* sortedA = (int*)(fws + o); o += (size_t)8 * BT_;
    int* segA    = (int*)(fws + o); o += 64;
    // ---- aliases (lifetimes disjoint; footprint = proven r8/r10 size)
    __bf16* Ag    = (__bf16*)hbuf;                          // [2048][<=512] bf16
    __bf16* hbufh = (__bf16*)(hbuf + (size_t)BT_ * D_ / 2); // [2048][1024] bf16
    __bf16* w1h   = (__bf16*)kbuf;                          // [4][Kpad][1024] bf16
    __bf16* w2h   = (__bf16*)vbuf;                          // [4][1024][512] bf16
    __bf16* w2e_h = (__bf16*)vbuf;                          // emb_w2 bf16 (pre-loop)
    __bf16* woe_h = (__bf16*)kbuf;                          // emb_wo bf16 (pre-loop)
    __bf16* outw_h= (__bf16*)kbuf;                          // out_w bf16 (post-loop)
    float* qbuf  = pbuf;
    float* attno = hbuf;                                    // attn phase only
    float* tmpo  = hbuf + (size_t)BT_ * D_;

    // h = relu(x@emb_w1+b1) — exact f32 (feeds routing)
    gemm80_k<<<dim3(HID_ / 64, BT_ / 64, 1), 256, 0, stream>>>(x, emb_w1, emb_b1, hbuf);
    wr2_k<<<256, 256, 0, stream>>>(emb_w2, f0_router, f_router, R2);
    routerall_k<<<RBLK_, 256, 0, stream>>>(hbuf, R2, seqlen, eid, gatev, impPart);
    bucketall_k<<<8, 256, 0, stream>>>(eid, sortedA, segA);
    // embed head: pre-convert B (N=4096 f32 B would thrash XCD L2), then GEMM
    cvtw_k<<<256, 256, 0, stream>>>(emb_w2, w2e_h, 9, 10, HID_);
    cvtw_k<<<1024, 256, 0, stream>>>(emb_wo, woe_h, 12, 9, D_);
    dgemm_k<false,true><<<dim3(D_ / 64, BT_ / 128, 1), 256, 0, stream>>>(
        hbuf, w2e_h, nullptr, embedF, D_, HID_);
    dgemm_k<false,true><<<dim3(OUT_ / 64, BT_ / 128, 1), 256, 0, stream>>>(
        embedF, woe_h, nullptr, out1, OUT_, D_);
    // hbuf (h) dead from here.

    for (int l = 0; l < 8; l++) {
        const float* w1  = (l == 0) ? f0_w1 : f_w1 + (size_t)(l-1) * E_ * D_ * HID_;
        const float* b1p = (l == 0) ? f0_b1 : f_b1 + (size_t)(l-1) * E_ * HID_;
        const float* w2  = (l == 0) ? f0_w2 : f_w2 + (size_t)(l-1) * E_ * HID_ * D_;
        const float* fbp = (l == 0) ? f0_fb : f_fb + (size_t)(l-1) * 4 * D_;
        const float* fap = (l == 0) ? f0_fa : f_fa + (size_t)(l-1) * 1 * D_;
        const float* Ain = (l == 0) ? x : curB;
        int lda  = (l == 0) ? IN_ : D_;
        int Ks   = (l == 0) ? IN_ : D_;
        int Kp   = (l == 0) ? 128 : 512;
        int kpsh = (l == 0) ? 7 : 9;
        const int* seg = segA + l * 8;
        const int* sorted = sortedA + l * BT_;

        // fused prep: w1 cvt | w2 cvt | A gather — one launch, 16x reuse kept
        int nb1 = E_ * Kp * HID_ / 8 / 256;
        int nb2 = E_ * HID_ * D_ / 8 / 256;
        int nb3 = BT_ * Kp / 8 / 256;
        prep_k<<<nb1 + nb2 + nb3, 256, 0, stream>>>(
            w1, w2, Ain, lda, sorted, w1h, w2h, Ag, kpsh, Ks, nb1, nb2);

        egemm_k<true><<<dim3(HID_/64, BT_/64, E_), 256, 0, stream>>>(
            Ag, w1h, b1p, hbufh, nullptr, HID_, Kp, seg, nullptr, nullptr);
        egemm_k<false><<<dim3(D_/64, BT_/64, E_), 256, 0, stream>>>(
            hbufh, w2h, nullptr, nullptr, pbuf, D_, HID_, seg, sorted,
            gatev + l * BT_);
        fsmn_k<<<BT_*D_/256, 256, 0, stream>>>(pbuf, fbp, fap, curB,
                                               (l > 0) ? 1 : 0, (l == 3) ? 1 : 0);

        if (l == 3 || l == 7) {
            int ab = (l == 3) ? 0 : 1;
            const float* wq = attn_wq + (size_t)ab * D_ * D_;
            const float* wk = attn_wk + (size_t)ab * D_ * D_;
            const float* wv = attn_wv + (size_t)ab * D_ * D_;
            const float* wo = attn_wo + (size_t)ab * D_ * D_;
            const float* mk = attn_mk + (size_t)ab * M_ * D_;
            const float* mv = attn_mv + (size_t)ab * M_ * D_;
            const float* g  = ln_g + (size_t)ab * D_;
            const float* bb = ln_b + (size_t)ab * D_;

            // kbuf/vbuf (w1h/w2h) dead now; qkv overwrites them with K/V.
            qkv_k<<<dim3(3 * D_ / MBN, BT_ / MBM, 1), 256, 0, stream>>>(
                curB, wq, wk, wv, qbuf, kbuf, vbuf);
            attn_k<<<dim3(T_/QR, H_, B_), 256, 0, stream>>>(
                qbuf, kbuf, vbuf, mk, mv, seqlen, attno);
            // wo is 1MB f32 -> L2-resident; f32-B GEMM, no convert launch
            dgemm_k<false,false><<<dim3(D_ / 64, BT_ / 128, 1), 256, 0, stream>>>(
                attno, wo, nullptr, tmpo, D_, D_);
            ln_k<<<BT_/4, 256, 0, stream>>>(tmpo, g, bb, curB);
        }
    }

    cvtw_k<<<1024, 256, 0, stream>>>(out_w, outw_h, 12, 9, D_);
    dgemm_k<true,true><<<dim3(OUT_ / 64, BT_ / 128, 1), 256, 0, stream>>>(
        curB, outw_h, out_b, out0, OUT_, D_);
    aux_k<<<1, 256, 0, stream>>>(impPart, out2);
}